// Round 2
// baseline (366.017 us; speedup 1.0000x reference)
//
#include <hip/hip_runtime.h>
#include <hip/hip_bf16.h>

typedef _Float16 f16;
typedef _Float16 f16x4 __attribute__((ext_vector_type(4)));
typedef _Float16 f16x8 __attribute__((ext_vector_type(8)));
typedef float    f32x4 __attribute__((ext_vector_type(4)));
typedef float    f32x16 __attribute__((ext_vector_type(16)));

static __device__ __forceinline__ float bf2f(__hip_bfloat16 x) { return __bfloat162float(x); }
// dual-dtype float load/store: f32flag=1 -> float*, else bf16*
static __device__ __forceinline__ float ldf(const void* p, long i, int f32flag) {
    return f32flag ? ((const float*)p)[i] : bf2f(((const __hip_bfloat16*)p)[i]);
}
static __device__ __forceinline__ void stf(void* p, long i, int f32flag, float v) {
    if (f32flag) ((float*)p)[i] = v;
    else ((__hip_bfloat16*)p)[i] = __float2bfloat16(v);
}
// async global->LDS, 16B per lane; LDS dest is wave-uniform base + lane*16
static __device__ __forceinline__ void gl2lds16(const f16* g, f16* l) {
    __builtin_amdgcn_global_load_lds(
        (const __attribute__((address_space(1))) unsigned int*)(const void*)g,
        (__attribute__((address_space(3))) unsigned int*)(void*)l, 16, 0, 0);
}

// ---------------- workspace layout (bytes) ----------------
#define OFF_LOGITS 0L                               // S/logits: 32000 x 1024 f16
#define SZ_LOGITS  (32000L * 1024 * 2)
#define OFF_FEAT   (OFF_LOGITS + SZ_LOGITS)         // feat: 32000 x 768 f16
#define SZ_FEAT    (32000L * 768 * 2)
#define OFF_ATTF   (OFF_FEAT + SZ_FEAT)             // att_feat: 32000 x 768 f16
#define SZ_ATTF    (32000L * 768 * 2)
#define OFF_AWT    (OFF_ATTF + SZ_ATTF)             // attn_w^T: 1024 x 768 f16 (rows>=999 zero)
#define SZ_AWT     (1024L * 768 * 2)
#define OFF_WCT    (OFF_AWT + SZ_AWT)               // Wc^T: 128 x 1536 f16 (rows>=75 zero)
#define SZ_WCT     (128L * 1536 * 2)
#define OFF_BIAS   (OFF_WCT + SZ_WCT)               // f32[128]
#define OFF_AB     (OFF_BIAS + 512)                 // attn_b as f32[1024]
#define OFF_FLAG   (OFF_AB + 4096)                  // int flags[2]
#define OFF_FEATT  (OFF_FLAG + 64)                  // feat^T per batch: 32 x 768 x 1024 f16
#define SZ_FEATT   (32L * 768 * 1024 * 2)
#define NEED_A     (OFF_FEATT + SZ_FEATT)           // ~216 MB

// ---------------- detection (cheap sampling) ----------------
__global__ void detect_kernel(const unsigned int* __restrict__ fv,
                              const unsigned int* __restrict__ m,
                              int mwords, int* __restrict__ flags)
{
    __shared__ int cnt, bits;
    int t = threadIdx.x;
    if (t == 0) { cnt = 0; bits = 0; }
    __syncthreads();
    int c = 0;
    for (int k = t; k < 2048; k += 256) {
        unsigned int w = fv[k];
        unsigned int h0 = w & 0xffffu, h1 = w >> 16;
        unsigned int e0 = (h0 >> 7) & 0xffu, e1 = (h1 >> 7) & 0xffu;
        c += (h0 == 0u || (e0 >= 100u && e0 <= 135u)) ? 1 : 0;
        c += (h1 == 0u || (e1 >= 100u && e1 <= 135u)) ? 1 : 0;
    }
    atomicAdd(&cnt, c);
    int lb = 0;
    for (int k = t; k < mwords; k += 256) {
        unsigned int w = m[k];
        if (w > 1u) lb |= 1;
        if ((k & 1) && w != 0u) lb |= 2;
        unsigned int lo = w & 0xffffu, hi = w >> 16;
        if (!((lo == 0u || lo == 0x3f80u) && (hi == 0u || hi == 0x3f80u))) lb |= 4;
        if (lo == 0x3f80u) lb |= 8;
    }
    if (lb) atomicOr(&bits, lb);
    __syncthreads();
    if (t == 0) {
        int b = bits, f;
        if (!(b & 1))      f = (b & 2) ? 0 : 3;
        else if (!(b & 4)) f = (b & 8) ? 2 : 4;
        else               f = 1;
        flags[0] = f;
        flags[1] = (cnt < 3900) ? 1 : 0;
    }
}

// ---------------- front: build_feat + attn_w transpose + weight packing (one dispatch) ----------------
// grid 2048: [0,512) feat gather; [512,1280) awT transpose; [1280,2048) wc/bias/abf32
__global__ __launch_bounds__(256) void front_kernel(
    const void* __restrict__ fv, const int* __restrict__ x_idx,
    const void* __restrict__ maskp, const int* __restrict__ flags,
    int xstride, int mstride, f16* __restrict__ feat,
    const void* __restrict__ attn_w,
    const void* __restrict__ cls_w, const void* __restrict__ cls_b,
    const void* __restrict__ reg_w, const void* __restrict__ reg_b,
    const void* __restrict__ attn_b,
    f16* __restrict__ awT, f16* __restrict__ wcT,
    float* __restrict__ biasc, float* __restrict__ abf32)
{
    int bid = blockIdx.x;
    int t = threadIdx.x;
    int isf = flags[1], fm = flags[0];
    if (bid < 512) {
        __shared__ f16 sfv[15360];                  // [(c*12+h)*20 + x]
        __shared__ int sx[756];
        __shared__ unsigned char sm[756];
        int b = bid >> 4, n0 = (bid & 15) * 63;
        int rows = min(63, 1000 - n0);
        if (isf) {                                  // f32: 3840 float4
            const float4* src = (const float4*)fv + (long)b * 3840;
            for (int k = t; k < 3840; k += 256) {
                float4 v = src[k];
                f16x4 h; h[0] = (f16)v.x; h[1] = (f16)v.y; h[2] = (f16)v.z; h[3] = (f16)v.w;
                *(f16x4*)&sfv[k * 4] = h;
            }
        } else {                                    // bf16: 1920 uint4
            const uint4* src = (const uint4*)fv + (long)b * 1920;
            for (int k = t; k < 1920; k += 256) {
                uint4 v = src[k];
                unsigned int wv[4] = {v.x, v.y, v.z, v.w};
                f16x8 h;
                #pragma unroll
                for (int j = 0; j < 4; j++) {
                    h[2 * j]     = (f16)__uint_as_float((wv[j] & 0xffffu) << 16);
                    h[2 * j + 1] = (f16)__uint_as_float(wv[j] & 0xffff0000u);
                }
                *(f16x8*)&sfv[k * 8] = h;
            }
        }
        for (int k = t; k < rows * 12; k += 256) {
            int n = k / 12, h = k - n * 12;
            sx[k] = x_idx[(long)(n0 + n) * xstride + h];
            long mb = (long)(n0 + n) * mstride + h;
            int mv;
            if (fm == 0)      mv = ((const int*)maskp)[mb] != 0;
            else if (fm == 1) mv = ((const unsigned char*)maskp)[mb] != 0;
            else if (fm == 2) mv = ((const unsigned short*)maskp)[mb] != 0;
            else if (fm == 3) mv = ((const int*)maskp)[mb * 2] != 0;
            else              mv = ((const unsigned int*)maskp)[mb] != 0;
            sm[k] = (unsigned char)mv;
        }
        __syncthreads();
        for (int q = t; q < rows * 192; q += 256) {
            int n = q / 192, r = q - n * 192;
            int e0 = r * 4;
            f16x4 v;
            #pragma unroll
            for (int j = 0; j < 4; j++) {
                int e = e0 + j;
                int h = e % 12;
                int kk = n * 12 + h;
                v[j] = sm[kk] ? (f16)0.f : sfv[e * 20 + sx[kk]];
            }
            *(f16x4*)(feat + ((long)(b * 1000 + n0 + n)) * 768 + e0) = v;
        }
    } else if (bid < 1280) {
        // attn_w (768 x 999, ld 999) -> awT (1024 x 768, ld 768), rows>=999 zero
        __shared__ f16 tile[32][33];
        int tid = bid - 512;
        int c0 = (tid % 32) * 32, r0 = (tid / 32) * 32;    // c: 0..1023, r: 0..767
        int tx = t & 31, ty = t >> 5;
        #pragma unroll
        for (int i = ty; i < 32; i += 8) {
            int r = r0 + i, c = c0 + tx;
            float v = 0.f;
            if (r < 768 && c < 999) v = ldf(attn_w, (long)r * 999 + c, isf);
            tile[i][tx] = (f16)v;
        }
        __syncthreads();
        #pragma unroll
        for (int i = ty; i < 32; i += 8) {
            int oc = c0 + i, orw = r0 + tx;
            awT[(long)oc * 768 + orw] = tile[tx][i];
        }
    } else {
        int idx = (bid - 1280) * 256 + t;           // 128*1536 = 196608
        if (idx < 128 * 1536) {
            int c = idx / 1536, k = idx - c * 1536;
            float v = 0.f;
            if (c < 2)       v = ldf(cls_w, (long)k * 2 + c, isf);
            else if (c < 75) v = ldf(reg_w, (long)k * 73 + (c - 2), isf);
            wcT[idx] = (f16)v;                       // wcT[c][k], ld 1536
        }
        if (idx < 75)
            biasc[idx] = (idx < 2) ? ldf(cls_b, idx, isf) : ldf(reg_b, idx - 2, isf);
        if (idx < 1024)
            abf32[idx] = (idx < 999) ? ldf(attn_b, idx, isf) : 0.f;
    }
}

// ---------------- post: feat->featT transpose + softmax-scatter (one dispatch) ----------------
__global__ __launch_bounds__(256) void post_kernel(
    f16* __restrict__ buf, const float* __restrict__ abf32,
    const f16* __restrict__ feat, f16* __restrict__ featT)
{
    int bid = blockIdx.x;
    int t = threadIdx.x;
    if (bid < 24576) {
        if (!featT) return;
        __shared__ f16 tile[32][33];
        int bx = bid % 24, rq = bid / 24;
        int by = rq % 32, bz = rq / 32;
        int c0 = bx * 32, r0 = by * 32;
        int tx = t & 31, ty = t >> 5;
        const f16* src = feat + (long)bz * 768000;
        #pragma unroll
        for (int i = ty; i < 32; i += 8) {
            int r = r0 + i, c = c0 + tx;
            f16 v = (f16)0.f;
            if (r < 1000) v = src[(long)r * 768 + c];
            tile[i][tx] = v;
        }
        __syncthreads();
        f16* dst = featT + (long)bz * 786432;
        #pragma unroll
        for (int i = ty; i < 32; i += 8) {
            int oc = c0 + i, orw = r0 + tx;
            dst[(long)oc * 1024 + orw] = tile[tx][i];
        }
    } else {
        int rid = bid - 24576;
        int i = rid % 1000, b = rid / 1000;
        f16* row = buf + ((long)(b * 1000 + i)) * 1024;
        __shared__ float red[8];
        int k0 = t * 4;
        f16x4 rv = *(const f16x4*)(row + k0);        // all reads before any write
        float4 ab = *(const float4*)(abf32 + k0);
        float abv[4] = {ab.x, ab.y, ab.z, ab.w};
        float v[4];
        float lmax = -3.4e38f;
        #pragma unroll
        for (int j = 0; j < 4; j++) {
            int k = k0 + j;
            float x = (k < 999) ? (float)rv[j] + abv[j] : -3.4e38f;
            v[j] = x;
            lmax = fmaxf(lmax, x);
        }
        #pragma unroll
        for (int o = 32; o > 0; o >>= 1) lmax = fmaxf(lmax, __shfl_down(lmax, o, 64));
        if ((t & 63) == 0) red[t >> 6] = lmax;
        __syncthreads();
        float gmax = fmaxf(fmaxf(red[0], red[1]), fmaxf(red[2], red[3]));
        float lsum = 0.f;
        #pragma unroll
        for (int j = 0; j < 4; j++) {
            int k = k0 + j;
            float e = (k < 999) ? __expf(v[j] - gmax) : 0.f;
            v[j] = e;
            lsum += e;
        }
        #pragma unroll
        for (int o = 32; o > 0; o >>= 1) lsum += __shfl_down(lsum, o, 64);
        if ((t & 63) == 0) red[4 + (t >> 6)] = lsum;
        __syncthreads();
        float inv = 1.f / (red[4] + red[5] + red[6] + red[7]);
        #pragma unroll
        for (int j = 0; j < 4; j++) {
            int k = k0 + j;
            if (k < 999) row[k + (k >= i ? 1 : 0)] = (f16)(v[j] * inv);
        }
        if (t == 0) row[i] = (f16)0.f;               // zero diagonal
    }
}

// ---------------- 32x32x16 4-phase MFMA GEMM ----------------
// 512 thr = 8 waves (WAVES_M x WAVES_N), per-wave WR x WC tiles of 32x32.
// BK=64 -> 4 k-steps of 16 = 4 phases/K-tile. Per phase: {ds_read WR+WC frags
// | stage 2 gl2lds units} -> barrier -> lgkmcnt(0) -> 8 MFMA -> barrier.
// Staging in 64-row units (512thr x 16B = 4096 f16): tile t's p0-p2 stage
// units 2..U-1 of tile t+1; p3 (post-MFMA) stages units 0,1 of tile t+2 into
// the just-freed buffer, then vmcnt(2) completes all of t+1 (oldest) while
// t+2's first 2 stay in flight. Tail tiles clamp the K-source (harmless).
#define SB8   __builtin_amdgcn_sched_barrier(0)
#define BAR8  __builtin_amdgcn_s_barrier()
#define LGKM0 do { asm volatile("s_waitcnt lgkmcnt(0)" ::: "memory"); __builtin_amdgcn_sched_barrier(0); } while (0)
#define VM2   asm volatile("s_waitcnt vmcnt(2)" ::: "memory")

template<int TM, int TN, int WAVES_M, int WAVES_N, int WR, int WC, int AU, int BU>
__global__ __launch_bounds__(512, 2) void gemm32_kernel(
    const f16* __restrict__ A, int lda,
    const f16* __restrict__ Bt, int ldb,
    f16* __restrict__ C, int ldc,
    int M, int MT, int NT, int KT,
    long sA, long sB, long sC)
{
    __shared__ __align__(16) f16 As[2][TM * 64];
    __shared__ __align__(16) f16 Bs[2][TN * 64];
    constexpr int UNITS = AU + BU;
    int t = threadIdx.x;
    int nwg = gridDim.x;
    int orig = blockIdx.x;
    int xcd = orig & 7, lin = orig >> 3;
    int q8 = nwg >> 3, r8 = nwg & 7;                 // bijective XCD swizzle (m204)
    int wgid = (xcd < r8 ? xcd * (q8 + 1) : r8 * (q8 + 1) + (xcd - r8) * q8) + lin;
    int per_b = MT * NT;
    int bz = wgid / per_b;
    int rem = wgid - bz * per_b;
    int mt = rem / NT, nt = rem - mt * NT;
    int m0 = mt * TM, n0 = nt * TN;
    A  += (long)bz * sA;
    Bt += (long)bz * sB;
    C  += (long)bz * sC;
    int w = t >> 6, lane = t & 63;
    int wave_n = w % WAVES_N, wave_m = w / WAVES_N;
    int wmb = wave_m * WR * 32, wnb = wave_n * WC * 32;
    int l31 = lane & 31, lq2 = lane >> 5;
    int row0 = t >> 3, slot = t & 7;
    int csw = slot ^ (row0 & 7);                     // pre-swizzled global source

    f32x16 acc[WR][WC];
    #pragma unroll
    for (int i = 0; i < WR; i++)
        #pragma unroll
        for (int j = 0; j < WC; j++)
            #pragma unroll
            for (int r = 0; r < 16; r++) acc[i][j][r] = 0.f;

    f16x8 a_[WR], b_[WC];

    auto stage_u = [&](int u, int kt, int buf) {
        int ktc = kt < KT ? kt : KT - 1;
        if (u < AU) {
            const f16* gp = A + (long)(m0 + u * 64 + row0) * lda + ktc * 64 + csw * 8;
            gl2lds16(gp, &As[buf][u * 4096 + w * 512]);
        } else {
            int v = u - AU;
            const f16* gp = Bt + (long)(n0 + v * 64 + row0) * ldb + ktc * 64 + csw * 8;
            gl2lds16(gp, &Bs[buf][v * 4096 + w * 512]);
        }
    };

#define RD32(ks, buf) { \
    _Pragma("unroll") for (int i = 0; i < WR; i++) { \
        int r = wmb + i * 32 + l31; \
        int cc = ((ks) * 2 + lq2) ^ (r & 7); \
        a_[i] = *(const f16x8*)&As[buf][r * 64 + cc * 8]; } \
    _Pragma("unroll") for (int j = 0; j < WC; j++) { \
        int r = wnb + j * 32 + l31; \
        int cc = ((ks) * 2 + lq2) ^ (r & 7); \
        b_[j] = *(const f16x8*)&Bs[buf][r * 64 + cc * 8]; } }
#define MF32() { \
    __builtin_amdgcn_s_setprio(1); \
    _Pragma("unroll") for (int i = 0; i < WR; i++) \
    _Pragma("unroll") for (int j = 0; j < WC; j++) \
        acc[i][j] = __builtin_amdgcn_mfma_f32_32x32x16_f16(a_[i], b_[j], acc[i][j], 0, 0, 0); \
    __builtin_amdgcn_s_setprio(0); }

    // prologue: all units of tile0 -> buf0; units 0,1 of tile1 -> buf1
    #pragma unroll
    for (int u = 0; u < UNITS; u++) stage_u(u, 0, 0);
    stage_u(0, 1, 1); stage_u(1, 1, 1);
    VM2;                                             // tile0 complete, 2 in flight
    BAR8;

    for (int kt = 0; kt < KT; kt++) {
        int buf = kt & 1, nbuf = buf ^ 1;
        // phase 0
        SB8; RD32(0, buf); stage_u(2, kt + 1, nbuf); stage_u(3, kt + 1, nbuf);
        BAR8; LGKM0; MF32(); BAR8;
        // phase 1
        SB8; RD32(1, buf); stage_u(4, kt + 1, nbuf); stage_u(5, kt + 1, nbuf);
        BAR8; LGKM0; MF32(); BAR8;
        // phase 2
        SB8; RD32(2, buf); stage_u(6, kt + 1, nbuf);
        if constexpr (UNITS == 8) stage_u(7, kt + 1, nbuf);
        BAR8; LGKM0; MF32(); BAR8;
        // phase 3: after MFMA this buffer's data is consumed -> stage tile kt+2
        SB8; RD32(3, buf);
        BAR8; LGKM0; MF32();
        stage_u(0, kt + 2, buf); stage_u(1, kt + 2, buf);
        VM2;                                         // completes all of tile kt+1
        BAR8;
    }

    // epilogue: 32x32 C/D layout: col = lane&31, row = (reg&3)+8*(reg>>2)+4*(lane>>5)
    #pragma unroll
    for (int i = 0; i < WR; i++)
        #pragma unroll
        for (int j = 0; j < WC; j++)
            #pragma unroll
            for (int r = 0; r < 16; r++) {
                int gm = m0 + wmb + i * 32 + (r & 3) + 8 * (r >> 2) + 4 * lq2;
                int gn = n0 + wnb + j * 32 + l31;
                if (gm < M) C[(long)gm * ldc + gn] = (f16)acc[i][j][r];
            }
#undef RD32
#undef MF32
}

// ---------------- MFMA GEMM (legacy paths: GEMM3 BG + non-bigws fallback) ----------------
enum { OUT_F16 = 0, OUT_FINAL = 1 };

template<int MODE, bool CAT, bool BKM, int TM, int TN, int BK, int SWZ, bool BG>
__global__ __launch_bounds__(256, 2) void gemm_kernel(
    const f16* __restrict__ A, const f16* __restrict__ A2, int lda,
    const f16* __restrict__ Bt, int ldb,
    void* __restrict__ Cout, int ldc,
    int M, int Nc, int K,
    long sA, long sB, long sC,
    const float* __restrict__ bias, const void* __restrict__ anchors,
    const int* __restrict__ flags)
{
    int t = threadIdx.x;
    int bx, by, bz;
    if constexpr (SWZ == 2) {          // flat grid: ngroups m-groups x 4 n-blocks
        int bid = blockIdx.x;
        int xcd = bid & 7, s = bid >> 3;
        int g = xcd + 8 * (s >> 2);                  // XCD owns groups g == xcd (mod 8)
        if (g >= (M + TM - 1) / TM) return;
        by = g; bx = s & 3; bz = 0;
    } else if constexpr (SWZ == 3) {   // grid 768 flat: 8 XCD x 4 batches x (8m x 3n)
        int bid = blockIdx.x;
        int xcd = bid & 7, s = bid >> 3;             // s in [0,96)
        bz = xcd * 4 + s / 24;
        int wv = s % 24;
        by = wv / 3; bx = wv - by * 3;
    } else { bx = blockIdx.x; by = blockIdx.y; bz = blockIdx.z; }

    int m0 = by * TM, n0 = bx * TN;
    int z = bz;
    A  += (long)z * sA;
    if (CAT) A2 += (long)z * sA;
    Bt += (long)z * sB;
    int w = t >> 6, lane = t & 63;
    constexpr int NJ = (TM == 128 && TN == 256) ? 8 : ((TN == 256) ? 4 : ((TM == 128) ? 4 : 2));
    int wm = (TM == 128) ? (w & 1) * 64 : 0;
    int wn;
    if constexpr (TM == 128 && TN == 256) wn = (w >> 1) * 128;
    else if constexpr (TN == 256)         wn = w * 64;
    else if constexpr (TM == 128)         wn = (w >> 1) * 64;
    else                                  wn = w * 32;

    int lr = lane & 15, lq = lane >> 4;

    const f32x4 zero4 = {0.f, 0.f, 0.f, 0.f};
    f32x4 acc[4][NJ];
    #pragma unroll
    for (int i = 0; i < 4; i++)
        #pragma unroll
        for (int j = 0; j < NJ; j++) acc[i][j] = zero4;

    if constexpr (BG) {
        // A staged to LDS; B fragments straight from global (B must be L2-hot & row-padded)
        constexpr int CH  = BK / 8;
        constexpr int AI  = TM * BK / 2048;
        constexpr int RPO = 2048 / BK;
        __shared__ __align__(16) f16 As[TM * BK];
        int row0 = t / CH, slot = t % CH;
        int csw = slot ^ (row0 & (CH - 1));
        long aoffB = (long)(m0 + row0) * lda + csw * 8;
        for (int k0 = 0; k0 < K; k0 += BK) {
            const f16* Ak = A; int kk = k0;
            if (CAT && k0 >= 768) { Ak = A2; kk = k0 - 768; }
            __syncthreads();
            #pragma unroll
            for (int i = 0; i < AI; i++)
                gl2lds16(Ak + aoffB + (long)(i * RPO) * lda + kk, &As[i * 2048 + w * 512]);
            f16x8 ball[BK / 32][NJ];
            #pragma unroll
            for (int ks = 0; ks < BK / 32; ks++)
                #pragma unroll
                for (int j = 0; j < NJ; j++) {
                    int r = wn + j * 16 + lr;
                    ball[ks][j] = *(const f16x8*)(Bt + (long)r * ldb + k0 + (ks * 4 + lq) * 8);
                }
            __syncthreads();
            #pragma unroll
            for (int ks = 0; ks < BK / 32; ks++) {
                f16x8 af[4];
                #pragma unroll
                for (int i = 0; i < 4; i++) {
                    int r = wm + i * 16 + lr;
                    int cc = (lq + ks * 4) ^ (r & (CH - 1));
                    af[i] = *(const f16x8*)&As[r * BK + cc * 8];
                }
                #pragma unroll
                for (int i = 0; i < 4; i++)
                    #pragma unroll
                    for (int j = 0; j < NJ; j++)
                        acc[i][j] = __builtin_amdgcn_mfma_f32_16x16x32_f16(af[i], ball[ks][j], acc[i][j], 0, 0, 0);
            }
        }
    } else if constexpr (!BKM) {
        constexpr int CH  = BK / 8;                  // 16B chunks per row
        constexpr int AI  = TM * BK / 2048;          // staging ops (2048 elems each)
        constexpr int BI  = TN * BK / 2048;
        constexpr int RPO = 2048 / BK;               // rows per staging op
        __shared__ __align__(16) f16 As[TM * BK];
        __shared__ __align__(16) f16 Bs[TN * BK];
        int row0 = t / CH, slot = t % CH;
        int csw = slot ^ (row0 & (CH - 1));
        long aoffB = (long)(m0 + row0) * lda + csw * 8;
        long boffB = (long)(n0 + row0) * ldb + csw * 8;
        for (int k0 = 0; k0 < K; k0 += BK) {
            const f16* Ak = A; int kk = k0;
            if (CAT && k0 >= 768) { Ak = A2; kk = k0 - 768; }
            __syncthreads();
            #pragma unroll
            for (int i = 0; i < AI; i++)
                gl2lds16(Ak + aoffB + (long)(i * RPO) * lda + kk, &As[i * 2048 + w * 512]);
            #pragma unroll
            for (int i = 0; i < BI; i++)
                gl2lds16(Bt + boffB + (long)(i * RPO) * ldb + k0, &Bs[i * 2048 + w * 512]);
            __syncthreads();                         // drains vmcnt before barrier
            #pragma unroll
            for (int ks = 0; ks < BK / 32; ks++) {
                f16x8 af[4], bfr[NJ];
                #pragma unroll
                for (int i = 0; i < 4; i++) {
                    int r = wm + i * 16 + lr;
                    int cc = (lq + ks * 4) ^ (r & (CH - 1));
                    af[i] = *(const f16x8*)&As[r * BK + cc * 8];
                }
                #pragma unroll
                for (int j = 0; j < NJ; j++) {
                    int r = wn + j * 16 + lr;
                    int cc = (lq + ks * 4) ^ (r & (CH - 1));
                    bfr[j] = *(const f16x8*)&Bs[r * BK + cc * 8];
                }
                #pragma unroll
                for (int i = 0; i < 4; i++)
                    #pragma unroll
                    for (int j = 0; j < NJ; j++)
                        acc[i][j] = __builtin_amdgcn_mfma_f32_16x16x32_f16(af[i], bfr[j], acc[i][j], 0, 0, 0);
            }
        }
    } else {
        __shared__ __align__(16) f16 As[128 * 40];
        __shared__ __align__(16) f16 Bs[32 * 132];
        const f16x8 zero8 = {(f16)0, (f16)0, (f16)0, (f16)0, (f16)0, (f16)0, (f16)0, (f16)0};
        const f16x4 zero4h = {(f16)0, (f16)0, (f16)0, (f16)0};
        for (int k0 = 0; k0 < K; k0 += 32) {
            __syncthreads();
            #pragma unroll
            for (int i = 0; i < 2; i++) {
                int q = t + i * 256;
                { int row = q >> 2, kc = (q & 3) * 8;
                  f16x8 av = zero8;
                  if ((m0 + row) < M && (k0 + kc) < K)
                      av = *(const f16x8*)(A + (long)(m0 + row) * lda + k0 + kc);
                  *(f16x8*)&As[row * 40 + kc] = av; }
                { int kr = q >> 4, nc = (q & 15) * 8;
                  f16x4 b0 = zero4h, b1 = zero4h;
                  if ((k0 + kr) < K && (n0 + nc) < Nc) {
                      const f16* p2 = Bt + (long)(k0 + kr) * ldb + n0 + nc;
                      b0 = *(const f16x4*)p2;
                      b1 = *(const f16x4*)(p2 + 4);
                  }
                  *(f16x4*)&Bs[kr * 132 + nc]     = b0;
                  *(f16x4*)&Bs[kr * 132 + nc + 4] = b1; }
            }
            __syncthreads();
            f16x8 af[4], bfr[NJ];
            #pragma unroll
            for (int i = 0; i < 4; i++)
                af[i] = *(const f16x8*)&As[(wm + i * 16 + lr) * 40 + lq * 8];
            #pragma unroll
            for (int j = 0; j < NJ; j++)
                #pragma unroll
                for (int jj = 0; jj < 8; jj++)
                    bfr[j][jj] = Bs[(lq * 8 + jj) * 132 + wn + j * 16 + lr];
            #pragma unroll
            for (int i = 0; i < 4; i++)
                #pragma unroll
                for (int j = 0; j < NJ; j++)
                    acc[i][j] = __builtin_amdgcn_mfma_f32_16x16x32_f16(af[i], bfr[j], acc[i][j], 0, 0, 0);
        }
    }

    int isf = (MODE == OUT_FINAL) ? flags[1] : 0;
    #pragma unroll
    for (int i = 0; i < 4; i++) {
        #pragma unroll
        for (int j = 0; j < NJ; j++) {
            #pragma unroll
            for (int r = 0; r < 4; r++) {
                int gm = m0 + wm + i * 16 + lq * 4 + r;   // C/D: row = quad*4+reg
                int gn = n0 + wn + j * 16 + lr;           //      col = lane&15
                if (MODE == OUT_F16) {
                    if (gm < M && gn < Nc)
                        ((f16*)Cout)[(long)z * sC + (long)gm * ldc + gn] = (f16)acc[i][j][r];
                } else {
                    if (gn < Nc) {                         // Nc=75 real cols
                        float v = acc[i][j][r] + bias[gn];
                        int oc = (gn < 2) ? gn : gn + 2;   // skip anchor cols 2,3
                        if (gn >= 2) v += ldf(anchors, (long)(gm % 1000) * 77 + oc, isf);
                        stf(Cout, (long)gm * 77 + oc, isf, v);
                    } else if (gn < 77) {                  // wasted lanes fill anchor cols 2,3
                        int oc = gn - 73;                  // 75->2, 76->3
                        stf(Cout, (long)gm * 77 + oc, isf,
                            ldf(anchors, (long)(gm % 1000) * 77 + oc, isf));
                    }
                }
            }
        }
    }
}

extern "C" void kernel_launch(void* const* d_in, const int* in_sizes, int n_in,
                              void* d_out, int out_size, void* d_ws, size_t ws_size,
                              hipStream_t stream)
{
    const void* fv      = d_in[0];
    const void* attn_w  = d_in[1];
    const void* attn_b  = d_in[2];
    const void* cls_w   = d_in[3];
    const void* cls_b   = d_in[4];
    const void* reg_w   = d_in[5];
    const void* reg_b   = d_in[6];
    const void* anchors = d_in[7];
    const int*  x_idx   = (const int*)d_in[10];
    const void* maskp   = d_in[11];
    int xstride = (in_sizes[10] < 768000) ? 12 : 768;   // un-broadcast fallback
    int mstride = (in_sizes[11] < 768000) ? 12 : 768;
    int mwords  = in_sizes[11] / 4;                      // int8 worst case, stay in bounds
    if (mwords > 4096) mwords = 4096;

    char* ws = (char*)d_ws;
    f16*   logits = (f16*)(ws + OFF_LOGITS);
    f16*   feat   = (f16*)(ws + OFF_FEAT);
    f16*   attf   = (f16*)(ws + OFF_ATTF);
    f16*   awT    = (f16*)(ws + OFF_AWT);
    f16*   wcT    = (f16*)(ws + OFF_WCT);
    float* biasc  = (float*)(ws + OFF_BIAS);
    float* abf32  = (float*)(ws + OFF_AB);
    int*   flags  = (int*)(ws + OFF_FLAG);
    f16*   featT  = (f16*)(ws + OFF_FEATT);
    bool bigws = ws_size >= (size_t)NEED_A;

    detect_kernel<<<dim3(1), dim3(256), 0, stream>>>(
        (const unsigned int*)fv, (const unsigned int*)maskp, mwords, flags);
    front_kernel<<<dim3(2048), dim3(256), 0, stream>>>(
        fv, x_idx, maskp, flags, xstride, mstride, feat,
        attn_w, cls_w, cls_b, reg_w, reg_b, attn_b, awT, wcT, biasc, abf32);

    // GEMM1: logits = feat @ attn_w  (M=32000=125x256, N=1024=4x256, K=768=12x64)
    // 32x32x16 shape, waves 2Mx4N (wave 128x64), 500 blocks x 512 thr
    gemm32_kernel<256, 256, 2, 4, 4, 2, 4, 4><<<dim3(500), dim3(512), 0, stream>>>(
        feat, 768, awT, 768, logits, 1024, 32000, 125, 4, 12, 0L, 0L, 0L);
    // transpose feat->featT + softmax-scatter in one dispatch
    post_kernel<<<dim3(24576 + 32000), dim3(256), 0, stream>>>(
        logits, abf32, feat, bigws ? featT : nullptr);
    // GEMM2 (batched): att_feat = S @ feat  (M=1000 (4 tiles w/ tail), N=768=4x192,
    // K=1024=16x64, 32 batches) -> 512 blocks x 512 thr = exactly 2 rounds.
    // 32x32x16 shape, waves 4Mx2N (wave 64x96), LDS 112 KiB.
    if (bigws) {
        gemm32_kernel<256, 192, 4, 2, 2, 3, 4, 3><<<dim3(512), dim3(512), 0, stream>>>(
            logits, 1024, featT, 1024, attf, 768, 1000, 4, 4, 16,
            1024000L, 786432L, 768000L);
    } else {
        gemm_kernel<OUT_F16, false, true, 128, 128, 32, 0, false><<<dim3(6, 8, 32), dim3(256), 0, stream>>>(
            logits, nullptr, 1024, feat, 768, attf, 768, 1000, 768, 1000,
            1024000L, 768000L, 768000L, nullptr, nullptr, flags);
    }
    // GEMM3: out = [att_feat | feat] @ Wc, fused epilogue; lean BG path (B=wcT from L2),
    // A-only LDS (16 KB), BK=128, TM=64/TN=128 -> 500 blocks, ~3 blocks/CU
    gemm_kernel<OUT_FINAL, true, false, 64, 128, 128, 0, true><<<dim3(1, 500, 1), dim3(256), 0, stream>>>(
        attf, feat, 768, wcT, 1536, d_out, 77, 32000, 75, 1536, 0, 0, 0,
        biasc, anchors, flags);
}

// Round 3
// 356.935 us; speedup vs baseline: 1.0254x; 1.0254x over previous
//
#include <hip/hip_runtime.h>
#include <hip/hip_bf16.h>

typedef _Float16 f16;
typedef _Float16 f16x4 __attribute__((ext_vector_type(4)));
typedef _Float16 f16x8 __attribute__((ext_vector_type(8)));
typedef float    f32x4 __attribute__((ext_vector_type(4)));

static __device__ __forceinline__ float bf2f(__hip_bfloat16 x) { return __bfloat162float(x); }
// dual-dtype float load/store: f32flag=1 -> float*, else bf16*
static __device__ __forceinline__ float ldf(const void* p, long i, int f32flag) {
    return f32flag ? ((const float*)p)[i] : bf2f(((const __hip_bfloat16*)p)[i]);
}
static __device__ __forceinline__ void stf(void* p, long i, int f32flag, float v) {
    if (f32flag) ((float*)p)[i] = v;
    else ((__hip_bfloat16*)p)[i] = __float2bfloat16(v);
}
// async global->LDS, 16B per lane; LDS dest is wave-uniform base + lane*16
static __device__ __forceinline__ void gl2lds16(const f16* g, f16* l) {
    __builtin_amdgcn_global_load_lds(
        (const __attribute__((address_space(1))) unsigned int*)(const void*)g,
        (__attribute__((address_space(3))) unsigned int*)(void*)l, 16, 0, 0);
}

// ---------------- workspace layout (bytes) ----------------
#define OFF_LOGITS 0L                               // S/logits: 32000 x 1024 f16
#define SZ_LOGITS  (32000L * 1024 * 2)
#define OFF_FEAT   (OFF_LOGITS + SZ_LOGITS)         // feat: 32000 x 768 f16
#define SZ_FEAT    (32000L * 768 * 2)
#define OFF_ATTF   (OFF_FEAT + SZ_FEAT)             // att_feat: 32000 x 768 f16
#define SZ_ATTF    (32000L * 768 * 2)
#define OFF_AWT    (OFF_ATTF + SZ_ATTF)             // attn_w^T: 1024 x 768 f16 (rows>=999 zero)
#define SZ_AWT     (1024L * 768 * 2)
#define OFF_WCT    (OFF_AWT + SZ_AWT)               // Wc^T: 128 x 1536 f16 (rows>=75 zero)
#define SZ_WCT     (128L * 1536 * 2)
#define OFF_BIAS   (OFF_WCT + SZ_WCT)               // f32[128]
#define OFF_AB     (OFF_BIAS + 512)                 // attn_b as f32[1024]
#define OFF_FLAG   (OFF_AB + 4096)                  // int flags[2]
#define OFF_FEATT  (OFF_FLAG + 64)                  // feat^T per batch: 32 x 768 x 1024 f16
#define SZ_FEATT   (32L * 768 * 1024 * 2)
#define NEED_A     (OFF_FEATT + SZ_FEATT)           // ~216 MB

// ---------------- detection (cheap sampling) ----------------
__global__ void detect_kernel(const unsigned int* __restrict__ fv,
                              const unsigned int* __restrict__ m,
                              int mwords, int* __restrict__ flags)
{
    __shared__ int cnt, bits;
    int t = threadIdx.x;
    if (t == 0) { cnt = 0; bits = 0; }
    __syncthreads();
    int c = 0;
    for (int k = t; k < 2048; k += 256) {
        unsigned int w = fv[k];
        unsigned int h0 = w & 0xffffu, h1 = w >> 16;
        unsigned int e0 = (h0 >> 7) & 0xffu, e1 = (h1 >> 7) & 0xffu;
        c += (h0 == 0u || (e0 >= 100u && e0 <= 135u)) ? 1 : 0;
        c += (h1 == 0u || (e1 >= 100u && e1 <= 135u)) ? 1 : 0;
    }
    atomicAdd(&cnt, c);
    int lb = 0;
    for (int k = t; k < mwords; k += 256) {
        unsigned int w = m[k];
        if (w > 1u) lb |= 1;
        if ((k & 1) && w != 0u) lb |= 2;
        unsigned int lo = w & 0xffffu, hi = w >> 16;
        if (!((lo == 0u || lo == 0x3f80u) && (hi == 0u || hi == 0x3f80u))) lb |= 4;
        if (lo == 0x3f80u) lb |= 8;
    }
    if (lb) atomicOr(&bits, lb);
    __syncthreads();
    if (t == 0) {
        int b = bits, f;
        if (!(b & 1))      f = (b & 2) ? 0 : 3;
        else if (!(b & 4)) f = (b & 8) ? 2 : 4;
        else               f = 1;
        flags[0] = f;
        flags[1] = (cnt < 3900) ? 1 : 0;
    }
}

// ---------------- front: build_feat + attn_w transpose + weight packing (one dispatch) ----------------
// grid 2048: [0,512) feat gather; [512,1280) awT transpose; [1280,2048) wc/bias/abf32
__global__ __launch_bounds__(256) void front_kernel(
    const void* __restrict__ fv, const int* __restrict__ x_idx,
    const void* __restrict__ maskp, const int* __restrict__ flags,
    int xstride, int mstride, f16* __restrict__ feat,
    const void* __restrict__ attn_w,
    const void* __restrict__ cls_w, const void* __restrict__ cls_b,
    const void* __restrict__ reg_w, const void* __restrict__ reg_b,
    const void* __restrict__ attn_b,
    f16* __restrict__ awT, f16* __restrict__ wcT,
    float* __restrict__ biasc, float* __restrict__ abf32)
{
    int bid = blockIdx.x;
    int t = threadIdx.x;
    int isf = flags[1], fm = flags[0];
    if (bid < 512) {
        __shared__ f16 sfv[15360];                  // [(c*12+h)*20 + x]
        __shared__ int sx[756];
        __shared__ unsigned char sm[756];
        int b = bid >> 4, n0 = (bid & 15) * 63;
        int rows = min(63, 1000 - n0);
        if (isf) {                                  // f32: 3840 float4
            const float4* src = (const float4*)fv + (long)b * 3840;
            for (int k = t; k < 3840; k += 256) {
                float4 v = src[k];
                f16x4 h; h[0] = (f16)v.x; h[1] = (f16)v.y; h[2] = (f16)v.z; h[3] = (f16)v.w;
                *(f16x4*)&sfv[k * 4] = h;
            }
        } else {                                    // bf16: 1920 uint4
            const uint4* src = (const uint4*)fv + (long)b * 1920;
            for (int k = t; k < 1920; k += 256) {
                uint4 v = src[k];
                unsigned int wv[4] = {v.x, v.y, v.z, v.w};
                f16x8 h;
                #pragma unroll
                for (int j = 0; j < 4; j++) {
                    h[2 * j]     = (f16)__uint_as_float((wv[j] & 0xffffu) << 16);
                    h[2 * j + 1] = (f16)__uint_as_float(wv[j] & 0xffff0000u);
                }
                *(f16x8*)&sfv[k * 8] = h;
            }
        }
        for (int k = t; k < rows * 12; k += 256) {
            int n = k / 12, h = k - n * 12;
            sx[k] = x_idx[(long)(n0 + n) * xstride + h];
            long mb = (long)(n0 + n) * mstride + h;
            int mv;
            if (fm == 0)      mv = ((const int*)maskp)[mb] != 0;
            else if (fm == 1) mv = ((const unsigned char*)maskp)[mb] != 0;
            else if (fm == 2) mv = ((const unsigned short*)maskp)[mb] != 0;
            else if (fm == 3) mv = ((const int*)maskp)[mb * 2] != 0;
            else              mv = ((const unsigned int*)maskp)[mb] != 0;
            sm[k] = (unsigned char)mv;
        }
        __syncthreads();
        for (int q = t; q < rows * 192; q += 256) {
            int n = q / 192, r = q - n * 192;
            int e0 = r * 4;
            f16x4 v;
            #pragma unroll
            for (int j = 0; j < 4; j++) {
                int e = e0 + j;
                int h = e % 12;
                int kk = n * 12 + h;
                v[j] = sm[kk] ? (f16)0.f : sfv[e * 20 + sx[kk]];
            }
            *(f16x4*)(feat + ((long)(b * 1000 + n0 + n)) * 768 + e0) = v;
        }
    } else if (bid < 1280) {
        // attn_w (768 x 999, ld 999) -> awT (1024 x 768, ld 768), rows>=999 zero
        __shared__ f16 tile[32][33];
        int tid = bid - 512;
        int c0 = (tid % 32) * 32, r0 = (tid / 32) * 32;    // c: 0..1023, r: 0..767
        int tx = t & 31, ty = t >> 5;
        #pragma unroll
        for (int i = ty; i < 32; i += 8) {
            int r = r0 + i, c = c0 + tx;
            float v = 0.f;
            if (r < 768 && c < 999) v = ldf(attn_w, (long)r * 999 + c, isf);
            tile[i][tx] = (f16)v;
        }
        __syncthreads();
        #pragma unroll
        for (int i = ty; i < 32; i += 8) {
            int oc = c0 + i, orw = r0 + tx;
            awT[(long)oc * 768 + orw] = tile[tx][i];
        }
    } else {
        int idx = (bid - 1280) * 256 + t;           // 128*1536 = 196608
        if (idx < 128 * 1536) {
            int c = idx / 1536, k = idx - c * 1536;
            float v = 0.f;
            if (c < 2)       v = ldf(cls_w, (long)k * 2 + c, isf);
            else if (c < 75) v = ldf(reg_w, (long)k * 73 + (c - 2), isf);
            wcT[idx] = (f16)v;                       // wcT[c][k], ld 1536
        }
        if (idx < 75)
            biasc[idx] = (idx < 2) ? ldf(cls_b, idx, isf) : ldf(reg_b, idx - 2, isf);
        if (idx < 1024)
            abf32[idx] = (idx < 999) ? ldf(attn_b, idx, isf) : 0.f;
    }
}

// ---------------- post: feat->featT transpose + softmax-scatter (one dispatch) ----------------
__global__ __launch_bounds__(256) void post_kernel(
    f16* __restrict__ buf, const float* __restrict__ abf32,
    const f16* __restrict__ feat, f16* __restrict__ featT)
{
    int bid = blockIdx.x;
    int t = threadIdx.x;
    if (bid < 24576) {
        if (!featT) return;
        __shared__ f16 tile[32][33];
        int bx = bid % 24, rq = bid / 24;
        int by = rq % 32, bz = rq / 32;
        int c0 = bx * 32, r0 = by * 32;
        int tx = t & 31, ty = t >> 5;
        const f16* src = feat + (long)bz * 768000;
        #pragma unroll
        for (int i = ty; i < 32; i += 8) {
            int r = r0 + i, c = c0 + tx;
            f16 v = (f16)0.f;
            if (r < 1000) v = src[(long)r * 768 + c];
            tile[i][tx] = v;
        }
        __syncthreads();
        f16* dst = featT + (long)bz * 786432;
        #pragma unroll
        for (int i = ty; i < 32; i += 8) {
            int oc = c0 + i, orw = r0 + tx;
            dst[(long)oc * 1024 + orw] = tile[tx][i];
        }
    } else {
        int rid = bid - 24576;
        int i = rid % 1000, b = rid / 1000;
        f16* row = buf + ((long)(b * 1000 + i)) * 1024;
        __shared__ float red[8];
        int k0 = t * 4;
        f16x4 rv = *(const f16x4*)(row + k0);        // all reads before any write
        float4 ab = *(const float4*)(abf32 + k0);
        float abv[4] = {ab.x, ab.y, ab.z, ab.w};
        float v[4];
        float lmax = -3.4e38f;
        #pragma unroll
        for (int j = 0; j < 4; j++) {
            int k = k0 + j;
            float x = (k < 999) ? (float)rv[j] + abv[j] : -3.4e38f;
            v[j] = x;
            lmax = fmaxf(lmax, x);
        }
        #pragma unroll
        for (int o = 32; o > 0; o >>= 1) lmax = fmaxf(lmax, __shfl_down(lmax, o, 64));
        if ((t & 63) == 0) red[t >> 6] = lmax;
        __syncthreads();
        float gmax = fmaxf(fmaxf(red[0], red[1]), fmaxf(red[2], red[3]));
        float lsum = 0.f;
        #pragma unroll
        for (int j = 0; j < 4; j++) {
            int k = k0 + j;
            float e = (k < 999) ? __expf(v[j] - gmax) : 0.f;
            v[j] = e;
            lsum += e;
        }
        #pragma unroll
        for (int o = 32; o > 0; o >>= 1) lsum += __shfl_down(lsum, o, 64);
        if ((t & 63) == 0) red[4 + (t >> 6)] = lsum;
        __syncthreads();
        float inv = 1.f / (red[4] + red[5] + red[6] + red[7]);
        #pragma unroll
        for (int j = 0; j < 4; j++) {
            int k = k0 + j;
            if (k < 999) row[k + (k >= i ? 1 : 0)] = (f16)(v[j] * inv);
        }
        if (t == 0) row[i] = (f16)0.f;               // zero diagonal
    }
}

// ---------------- 8-phase 256x256 MFMA GEMM (T2+T3+T4+T5) ----------------
// 512 thr = 8 waves (2M x 4N), per-wave 128x64 out, BK=64, dbuf LDS 128 KiB.
// Per iteration: 2 K-tiles, 8 phases; each phase: {ds_read frags | stage 1
// half-tile gl2lds} -> s_barrier -> lgkmcnt(0) -> setprio(1) 16 MFMA setprio(0)
// -> [vmcnt(4) at phases 3,7] -> s_barrier.
#define SB8   __builtin_amdgcn_sched_barrier(0)
#define BAR8  __builtin_amdgcn_s_barrier()
#define LGKM0 do { asm volatile("s_waitcnt lgkmcnt(0)" ::: "memory"); __builtin_amdgcn_sched_barrier(0); } while (0)
#define VM4   asm volatile("s_waitcnt vmcnt(4)" ::: "memory")

__global__ __launch_bounds__(512, 2) void gemm8p_kernel(
    const f16* __restrict__ A, int lda,
    const f16* __restrict__ Bt, int ldb,
    f16* __restrict__ C, int ldc,
    int M, int MT, int NT, int KT,
    long sA, long sB, long sC)
{
    __shared__ __align__(16) f16 As[2][16384];
    __shared__ __align__(16) f16 Bs[2][16384];
    int t = threadIdx.x;
    int nwg = gridDim.x;
    int orig = blockIdx.x;
    int xcd = orig & 7, lin = orig >> 3;
    int q8 = nwg >> 3, r8 = nwg & 7;                 // bijective XCD swizzle (m204)
    int wgid = (xcd < r8 ? xcd * (q8 + 1) : r8 * (q8 + 1) + (xcd - r8) * q8) + lin;
    int per_b = MT * NT;
    int bz = wgid / per_b;
    int rem = wgid - bz * per_b;
    int mt = rem / NT, nt = rem - mt * NT;
    int m0 = mt * 256, n0 = nt * 256;
    A  += (long)bz * sA;
    Bt += (long)bz * sB;
    C  += (long)bz * sC;
    int w = t >> 6, lane = t & 63;
    int wm = (w >> 2) * 128, wn = (w & 3) * 64;
    int lr = lane & 15, lq = lane >> 4;
    int row0 = t >> 3, slot = t & 7;
    int csw = slot ^ (row0 & 7);                     // pre-swizzled global source

    f32x4 acc[8][4];
    const f32x4 z4 = {0.f, 0.f, 0.f, 0.f};
    #pragma unroll
    for (int i = 0; i < 8; i++)
        #pragma unroll
        for (int j = 0; j < 4; j++) acc[i][j] = z4;

    f16x8 a_[2][2], b_[4][2];

// stage half h (128 rows, 2x gl2lds) of tile kt into buf; clamp kt for tail
#define STAGE_A8(kt, h, buf) do { \
    int ktc = (kt) < KT ? (kt) : KT - 1; \
    const f16* gp = A + (long)(m0 + (h) * 128 + row0) * lda + ktc * 64 + csw * 8; \
    gl2lds16(gp,                  &As[buf][(h) * 8192 + w * 512]); \
    gl2lds16(gp + 64 * (long)lda, &As[buf][(h) * 8192 + 4096 + w * 512]); \
} while (0)
#define STAGE_B8(kt, h, buf) do { \
    int ktc = (kt) < KT ? (kt) : KT - 1; \
    const f16* gp = Bt + (long)(n0 + (h) * 128 + row0) * ldb + ktc * 64 + csw * 8; \
    gl2lds16(gp,                  &Bs[buf][(h) * 8192 + w * 512]); \
    gl2lds16(gp + 64 * (long)ldb, &Bs[buf][(h) * 8192 + 4096 + w * 512]); \
} while (0)
#define RD_B8(buf) { \
    _Pragma("unroll") for (int n = 0; n < 4; n++) { \
        int r = wn + n * 16 + lr; int rb = r * 64; int x7 = r & 7; \
        _Pragma("unroll") for (int ks = 0; ks < 2; ks++) { \
            int cc = (lq + ks * 4) ^ x7; \
            b_[n][ks] = *(const f16x8*)&Bs[buf][rb + cc * 8]; } } }
#define RD_A8(q, buf) { \
    _Pragma("unroll") for (int m2 = 0; m2 < 2; m2++) { \
        int r = wm + ((q) * 2 + m2) * 16 + lr; int rb = r * 64; int x7 = r & 7; \
        _Pragma("unroll") for (int ks = 0; ks < 2; ks++) { \
            int cc = (lq + ks * 4) ^ x7; \
            a_[m2][ks] = *(const f16x8*)&As[buf][rb + cc * 8]; } } }
#define MFMA16(q) { \
    __builtin_amdgcn_s_setprio(1); \
    _Pragma("unroll") for (int ks = 0; ks < 2; ks++) \
    _Pragma("unroll") for (int m2 = 0; m2 < 2; m2++) \
    _Pragma("unroll") for (int n = 0; n < 4; n++) \
        acc[(q) * 2 + m2][n] = __builtin_amdgcn_mfma_f32_16x16x32_f16( \
            a_[m2][ks], b_[n][ks], acc[(q) * 2 + m2][n], 0, 0, 0); \
    __builtin_amdgcn_s_setprio(0); }

    // prologue: B(0),A(0) -> buf0; B(1) -> buf1; wait oldest 8, keep B(1) in flight
    STAGE_B8(0, 0, 0); STAGE_B8(0, 1, 0);
    STAGE_A8(0, 0, 0); STAGE_A8(0, 1, 0);
    STAGE_B8(1, 0, 1); STAGE_B8(1, 1, 1);
    VM4;
    BAR8;

    int NIT = KT >> 1;
    for (int it = 0; it < NIT; it++) {
        int t0 = 2 * it, t1 = t0 + 1;
        // phase 0: tile t0 (buf0): all B frags + A quad 0 | stage A0(t1)->buf1
        SB8; RD_B8(0); RD_A8(0, 0); STAGE_A8(t1, 0, 1);
        BAR8; LGKM0; MFMA16(0); BAR8;
        // phase 1
        SB8; RD_A8(1, 0); STAGE_A8(t1, 1, 1);
        BAR8; LGKM0; MFMA16(1); BAR8;
        // phase 2: Bs[0] consumed in phase 0 -> stage B(t0+2)
        SB8; RD_A8(2, 0); STAGE_B8(t0 + 2, 0, 0);
        BAR8; LGKM0; MFMA16(2); BAR8;
        // phase 3: counted wait: A(t1)+B(t1) must be the oldest 8 of 12
        SB8; RD_A8(3, 0); STAGE_B8(t0 + 2, 1, 0);
        BAR8; LGKM0; MFMA16(3); VM4; BAR8;
        // phase 4: tile t1 (buf1); As[0] consumed end of phase 3 -> stage A(t0+2)
        SB8; RD_B8(1); RD_A8(0, 1); STAGE_A8(t0 + 2, 0, 0);
        BAR8; LGKM0; MFMA16(0); BAR8;
        // phase 5
        SB8; RD_A8(1, 1); STAGE_A8(t0 + 2, 1, 0);
        BAR8; LGKM0; MFMA16(1); BAR8;
        // phase 6: Bs[1] consumed in phase 4 -> stage B(t1+2)
        SB8; RD_A8(2, 1); STAGE_B8(t1 + 2, 0, 1);
        BAR8; LGKM0; MFMA16(2); BAR8;
        // phase 7: counted wait: A(t0+2)+B(t0+2) oldest 8 of 12
        SB8; RD_A8(3, 1); STAGE_B8(t1 + 2, 1, 1);
        BAR8; LGKM0; MFMA16(3); VM4; BAR8;
    }

    // epilogue: C/D layout col=lane&15, row=(lane>>4)*4+reg
    #pragma unroll
    for (int m = 0; m < 8; m++)
        #pragma unroll
        for (int n = 0; n < 4; n++)
            #pragma unroll
            for (int r = 0; r < 4; r++) {
                int gm = m0 + wm + m * 16 + lq * 4 + r;
                int gn = n0 + wn + n * 16 + lr;
                if (gm < M) C[(long)gm * ldc + gn] = (f16)acc[m][n][r];
            }
#undef STAGE_A8
#undef STAGE_B8
#undef RD_B8
#undef RD_A8
#undef MFMA16
}

// ---------------- MFMA GEMM (legacy paths: GEMM3 BG + non-bigws fallback) ----------------
enum { OUT_F16 = 0, OUT_FINAL = 1 };

template<int MODE, bool CAT, bool BKM, int TM, int TN, int BK, int SWZ, bool BG>
__global__ __launch_bounds__(256, 2) void gemm_kernel(
    const f16* __restrict__ A, const f16* __restrict__ A2, int lda,
    const f16* __restrict__ Bt, int ldb,
    void* __restrict__ Cout, int ldc,
    int M, int Nc, int K,
    long sA, long sB, long sC,
    const float* __restrict__ bias, const void* __restrict__ anchors,
    const int* __restrict__ flags)
{
    int t = threadIdx.x;
    int bx, by, bz;
    if constexpr (SWZ == 2) {          // flat grid: ngroups m-groups x 4 n-blocks
        int bid = blockIdx.x;
        int xcd = bid & 7, s = bid >> 3;
        int g = xcd + 8 * (s >> 2);                  // XCD owns groups g == xcd (mod 8)
        if (g >= (M + TM - 1) / TM) return;
        by = g; bx = s & 3; bz = 0;
    } else if constexpr (SWZ == 3) {   // grid 768 flat: 8 XCD x 4 batches x (8m x 3n)
        int bid = blockIdx.x;
        int xcd = bid & 7, s = bid >> 3;             // s in [0,96)
        bz = xcd * 4 + s / 24;
        int wv = s % 24;
        by = wv / 3; bx = wv - by * 3;
    } else { bx = blockIdx.x; by = blockIdx.y; bz = blockIdx.z; }

    int m0 = by * TM, n0 = bx * TN;
    int z = bz;
    A  += (long)z * sA;
    if (CAT) A2 += (long)z * sA;
    Bt += (long)z * sB;
    int w = t >> 6, lane = t & 63;
    constexpr int NJ = (TM == 128 && TN == 256) ? 8 : ((TN == 256) ? 4 : ((TM == 128) ? 4 : 2));
    int wm = (TM == 128) ? (w & 1) * 64 : 0;
    int wn;
    if constexpr (TM == 128 && TN == 256) wn = (w >> 1) * 128;
    else if constexpr (TN == 256)         wn = w * 64;
    else if constexpr (TM == 128)         wn = (w >> 1) * 64;
    else                                  wn = w * 32;

    int lr = lane & 15, lq = lane >> 4;

    const f32x4 zero4 = {0.f, 0.f, 0.f, 0.f};
    f32x4 acc[4][NJ];
    #pragma unroll
    for (int i = 0; i < 4; i++)
        #pragma unroll
        for (int j = 0; j < NJ; j++) acc[i][j] = zero4;

    if constexpr (BG) {
        // A staged to LDS; B fragments straight from global (B must be L2-hot & row-padded)
        constexpr int CH  = BK / 8;
        constexpr int AI  = TM * BK / 2048;
        constexpr int RPO = 2048 / BK;
        __shared__ __align__(16) f16 As[TM * BK];
        int row0 = t / CH, slot = t % CH;
        int csw = slot ^ (row0 & (CH - 1));
        long aoffB = (long)(m0 + row0) * lda + csw * 8;
        for (int k0 = 0; k0 < K; k0 += BK) {
            const f16* Ak = A; int kk = k0;
            if (CAT && k0 >= 768) { Ak = A2; kk = k0 - 768; }
            __syncthreads();
            #pragma unroll
            for (int i = 0; i < AI; i++)
                gl2lds16(Ak + aoffB + (long)(i * RPO) * lda + kk, &As[i * 2048 + w * 512]);
            f16x8 ball[BK / 32][NJ];
            #pragma unroll
            for (int ks = 0; ks < BK / 32; ks++)
                #pragma unroll
                for (int j = 0; j < NJ; j++) {
                    int r = wn + j * 16 + lr;
                    ball[ks][j] = *(const f16x8*)(Bt + (long)r * ldb + k0 + (ks * 4 + lq) * 8);
                }
            __syncthreads();
            #pragma unroll
            for (int ks = 0; ks < BK / 32; ks++) {
                f16x8 af[4];
                #pragma unroll
                for (int i = 0; i < 4; i++) {
                    int r = wm + i * 16 + lr;
                    int cc = (lq + ks * 4) ^ (r & (CH - 1));
                    af[i] = *(const f16x8*)&As[r * BK + cc * 8];
                }
                #pragma unroll
                for (int i = 0; i < 4; i++)
                    #pragma unroll
                    for (int j = 0; j < NJ; j++)
                        acc[i][j] = __builtin_amdgcn_mfma_f32_16x16x32_f16(af[i], ball[ks][j], acc[i][j], 0, 0, 0);
            }
        }
    } else if constexpr (!BKM) {
        constexpr int CH  = BK / 8;                  // 16B chunks per row
        constexpr int AI  = TM * BK / 2048;          // staging ops (2048 elems each)
        constexpr int BI  = TN * BK / 2048;
        constexpr int RPO = 2048 / BK;               // rows per staging op
        __shared__ __align__(16) f16 As[TM * BK];
        __shared__ __align__(16) f16 Bs[TN * BK];
        int row0 = t / CH, slot = t % CH;
        int csw = slot ^ (row0 & (CH - 1));
        long aoffB = (long)(m0 + row0) * lda + csw * 8;
        long boffB = (long)(n0 + row0) * ldb + csw * 8;
        for (int k0 = 0; k0 < K; k0 += BK) {
            const f16* Ak = A; int kk = k0;
            if (CAT && k0 >= 768) { Ak = A2; kk = k0 - 768; }
            __syncthreads();
            #pragma unroll
            for (int i = 0; i < AI; i++)
                gl2lds16(Ak + aoffB + (long)(i * RPO) * lda + kk, &As[i * 2048 + w * 512]);
            #pragma unroll
            for (int i = 0; i < BI; i++)
                gl2lds16(Bt + boffB + (long)(i * RPO) * ldb + k0, &Bs[i * 2048 + w * 512]);
            __syncthreads();                         // drains vmcnt before barrier
            #pragma unroll
            for (int ks = 0; ks < BK / 32; ks++) {
                f16x8 af[4], bfr[NJ];
                #pragma unroll
                for (int i = 0; i < 4; i++) {
                    int r = wm + i * 16 + lr;
                    int cc = (lq + ks * 4) ^ (r & (CH - 1));
                    af[i] = *(const f16x8*)&As[r * BK + cc * 8];
                }
                #pragma unroll
                for (int j = 0; j < NJ; j++) {
                    int r = wn + j * 16 + lr;
                    int cc = (lq + ks * 4) ^ (r & (CH - 1));
                    bfr[j] = *(const f16x8*)&Bs[r * BK + cc * 8];
                }
                #pragma unroll
                for (int i = 0; i < 4; i++)
                    #pragma unroll
                    for (int j = 0; j < NJ; j++)
                        acc[i][j] = __builtin_amdgcn_mfma_f32_16x16x32_f16(af[i], bfr[j], acc[i][j], 0, 0, 0);
            }
        }
    } else {
        __shared__ __align__(16) f16 As[128 * 40];
        __shared__ __align__(16) f16 Bs[32 * 132];
        const f16x8 zero8 = {(f16)0, (f16)0, (f16)0, (f16)0, (f16)0, (f16)0, (f16)0, (f16)0};
        const f16x4 zero4h = {(f16)0, (f16)0, (f16)0, (f16)0};
        for (int k0 = 0; k0 < K; k0 += 32) {
            __syncthreads();
            #pragma unroll
            for (int i = 0; i < 2; i++) {
                int q = t + i * 256;
                { int row = q >> 2, kc = (q & 3) * 8;
                  f16x8 av = zero8;
                  if ((m0 + row) < M && (k0 + kc) < K)
                      av = *(const f16x8*)(A + (long)(m0 + row) * lda + k0 + kc);
                  *(f16x8*)&As[row * 40 + kc] = av; }
                { int kr = q >> 4, nc = (q & 15) * 8;
                  f16x4 b0 = zero4h, b1 = zero4h;
                  if ((k0 + kr) < K && (n0 + nc) < Nc) {
                      const f16* p2 = Bt + (long)(k0 + kr) * ldb + n0 + nc;
                      b0 = *(const f16x4*)p2;
                      b1 = *(const f16x4*)(p2 + 4);
                  }
                  *(f16x4*)&Bs[kr * 132 + nc]     = b0;
                  *(f16x4*)&Bs[kr * 132 + nc + 4] = b1; }
            }
            __syncthreads();
            f16x8 af[4], bfr[NJ];
            #pragma unroll
            for (int i = 0; i < 4; i++)
                af[i] = *(const f16x8*)&As[(wm + i * 16 + lr) * 40 + lq * 8];
            #pragma unroll
            for (int j = 0; j < NJ; j++)
                #pragma unroll
                for (int jj = 0; jj < 8; jj++)
                    bfr[j][jj] = Bs[(lq * 8 + jj) * 132 + wn + j * 16 + lr];
            #pragma unroll
            for (int i = 0; i < 4; i++)
                #pragma unroll
                for (int j = 0; j < NJ; j++)
                    acc[i][j] = __builtin_amdgcn_mfma_f32_16x16x32_f16(af[i], bfr[j], acc[i][j], 0, 0, 0);
        }
    }

    int isf = (MODE == OUT_FINAL) ? flags[1] : 0;
    #pragma unroll
    for (int i = 0; i < 4; i++) {
        #pragma unroll
        for (int j = 0; j < NJ; j++) {
            #pragma unroll
            for (int r = 0; r < 4; r++) {
                int gm = m0 + wm + i * 16 + lq * 4 + r;   // C/D: row = quad*4+reg
                int gn = n0 + wn + j * 16 + lr;           //      col = lane&15
                if (MODE == OUT_F16) {
                    if (gm < M && gn < Nc)
                        ((f16*)Cout)[(long)z * sC + (long)gm * ldc + gn] = (f16)acc[i][j][r];
                } else {
                    if (gn < Nc) {                         // Nc=75 real cols
                        float v = acc[i][j][r] + bias[gn];
                        int oc = (gn < 2) ? gn : gn + 2;   // skip anchor cols 2,3
                        if (gn >= 2) v += ldf(anchors, (long)(gm % 1000) * 77 + oc, isf);
                        stf(Cout, (long)gm * 77 + oc, isf, v);
                    } else if (gn < 77) {                  // wasted lanes fill anchor cols 2,3
                        int oc = gn - 73;                  // 75->2, 76->3
                        stf(Cout, (long)gm * 77 + oc, isf,
                            ldf(anchors, (long)(gm % 1000) * 77 + oc, isf));
                    }
                }
            }
        }
    }
}

extern "C" void kernel_launch(void* const* d_in, const int* in_sizes, int n_in,
                              void* d_out, int out_size, void* d_ws, size_t ws_size,
                              hipStream_t stream)
{
    const void* fv      = d_in[0];
    const void* attn_w  = d_in[1];
    const void* attn_b  = d_in[2];
    const void* cls_w   = d_in[3];
    const void* cls_b   = d_in[4];
    const void* reg_w   = d_in[5];
    const void* reg_b   = d_in[6];
    const void* anchors = d_in[7];
    const int*  x_idx   = (const int*)d_in[10];
    const void* maskp   = d_in[11];
    int xstride = (in_sizes[10] < 768000) ? 12 : 768;   // un-broadcast fallback
    int mstride = (in_sizes[11] < 768000) ? 12 : 768;
    int mwords  = in_sizes[11] / 4;                      // int8 worst case, stay in bounds
    if (mwords > 4096) mwords = 4096;

    char* ws = (char*)d_ws;
    f16*   logits = (f16*)(ws + OFF_LOGITS);
    f16*   feat   = (f16*)(ws + OFF_FEAT);
    f16*   attf   = (f16*)(ws + OFF_ATTF);
    f16*   awT    = (f16*)(ws + OFF_AWT);
    f16*   wcT    = (f16*)(ws + OFF_WCT);
    float* biasc  = (float*)(ws + OFF_BIAS);
    float* abf32  = (float*)(ws + OFF_AB);
    int*   flags  = (int*)(ws + OFF_FLAG);
    f16*   featT  = (f16*)(ws + OFF_FEATT);
    bool bigws = ws_size >= (size_t)NEED_A;

    detect_kernel<<<dim3(1), dim3(256), 0, stream>>>(
        (const unsigned int*)fv, (const unsigned int*)maskp, mwords, flags);
    front_kernel<<<dim3(2048), dim3(256), 0, stream>>>(
        fv, x_idx, maskp, flags, xstride, mstride, feat,
        attn_w, cls_w, cls_b, reg_w, reg_b, attn_b, awT, wcT, biasc, abf32);

    // GEMM1: logits = feat @ attn_w  (M=32000, N=1024, K=768), 8-phase 256^2.
    // SPLIT into two N-halves (250 blocks each, single round) for profiler
    // visibility of the second-tier kernels.
    gemm8p_kernel<<<dim3(250), dim3(512), 0, stream>>>(
        feat, 768, awT, 768, logits, 1024, 32000, 125, 2, 12, 0L, 0L, 0L);
    gemm8p_kernel<<<dim3(250), dim3(512), 0, stream>>>(
        feat, 768, awT + 512L * 768, 768, logits + 512, 1024, 32000, 125, 2, 12, 0L, 0L, 0L);
    // transpose feat->featT + softmax-scatter in one dispatch
    post_kernel<<<dim3(24576 + 32000), dim3(256), 0, stream>>>(
        logits, abf32, feat, bigws ? featT : nullptr);
    // GEMM2 (batched): att_feat = S @ feat  (M=1000, N=768, K=1024, 32 batches)
    // 8-phase 256^2, SPLIT into two batch-halves (192 blocks each, single round).
    if (bigws) {
        gemm8p_kernel<<<dim3(192), dim3(512), 0, stream>>>(
            logits, 1024, featT, 1024, attf, 768, 1000, 4, 3, 16,
            1024000L, 786432L, 768000L);
        gemm8p_kernel<<<dim3(192), dim3(512), 0, stream>>>(
            logits + 16L * 1024000L, 1024, featT + 16L * 786432L, 1024,
            attf + 16L * 768000L, 768, 1000, 4, 3, 16,
            1024000L, 786432L, 768000L);
    } else {
        gemm_kernel<OUT_F16, false, true, 128, 128, 32, 0, false><<<dim3(6, 8, 32), dim3(256), 0, stream>>>(
            logits, nullptr, 1024, feat, 768, attf, 768, 1000, 768, 1000,
            1024000L, 768000L, 768000L, nullptr, nullptr, flags);
    }
    // GEMM3: out = [att_feat | feat] @ Wc, fused epilogue; lean BG path (B=wcT from L2),
    // A-only LDS (16 KB), BK=128, TM=64/TN=128 -> 500 blocks, ~3 blocks/CU
    gemm_kernel<OUT_FINAL, true, false, 64, 128, 128, 0, true><<<dim3(1, 500, 1), dim3(256), 0, stream>>>(
        attf, feat, 768, wcT, 1536, d_out, 77, 32000, 75, 1536, 0, 0, 0,
        biasc, anchors, flags);
}

// Round 4
// 338.708 us; speedup vs baseline: 1.0806x; 1.0538x over previous
//
#include <hip/hip_runtime.h>
#include <hip/hip_bf16.h>

typedef _Float16 f16;
typedef _Float16 f16x4 __attribute__((ext_vector_type(4)));
typedef _Float16 f16x8 __attribute__((ext_vector_type(8)));
typedef float    f32x4 __attribute__((ext_vector_type(4)));

static __device__ __forceinline__ float bf2f(__hip_bfloat16 x) { return __bfloat162float(x); }
// dual-dtype float load/store: f32flag=1 -> float*, else bf16*
static __device__ __forceinline__ float ldf(const void* p, long i, int f32flag) {
    return f32flag ? ((const float*)p)[i] : bf2f(((const __hip_bfloat16*)p)[i]);
}
static __device__ __forceinline__ void stf(void* p, long i, int f32flag, float v) {
    if (f32flag) ((float*)p)[i] = v;
    else ((__hip_bfloat16*)p)[i] = __float2bfloat16(v);
}
// async global->LDS, 16B per lane; LDS dest is wave-uniform base + lane*16
static __device__ __forceinline__ void gl2lds16(const f16* g, f16* l) {
    __builtin_amdgcn_global_load_lds(
        (const __attribute__((address_space(1))) unsigned int*)(const void*)g,
        (__attribute__((address_space(3))) unsigned int*)(void*)l, 16, 0, 0);
}

// ---------------- workspace layout (bytes) ----------------
#define OFF_LOGITS 0L                               // S/logits: 32000 x 1024 f16
#define SZ_LOGITS  (32000L * 1024 * 2)
#define OFF_FEAT   (OFF_LOGITS + SZ_LOGITS)         // feat: 32000 x 768 f16
#define SZ_FEAT    (32000L * 768 * 2)
#define OFF_ATTF   (OFF_FEAT + SZ_FEAT)             // att_feat: 32000 x 768 f16
#define SZ_ATTF    (32000L * 768 * 2)
#define OFF_AWT    (OFF_ATTF + SZ_ATTF)             // attn_w^T: 1024 x 768 f16 (rows>=999 zero)
#define SZ_AWT     (1024L * 768 * 2)
#define OFF_WCT    (OFF_AWT + SZ_AWT)               // Wc^T: 128 x 1536 f16 (rows>=75 zero)
#define SZ_WCT     (128L * 1536 * 2)
#define OFF_BIAS   (OFF_WCT + SZ_WCT)               // f32[128]
#define OFF_AB     (OFF_BIAS + 512)                 // attn_b as f32[1024]
#define OFF_FLAG   (OFF_AB + 4096)                  // int flags[2]
#define OFF_FEATT  (OFF_FLAG + 64)                  // feat^T per batch: 32 x 768 x 1024 f16
#define SZ_FEATT   (32L * 768 * 1024 * 2)
#define NEED_A     (OFF_FEATT + SZ_FEATT)           // ~216 MB

// ---------------- detection (cheap sampling) ----------------
__global__ void detect_kernel(const unsigned int* __restrict__ fv,
                              const unsigned int* __restrict__ m,
                              int mwords, int* __restrict__ flags)
{
    __shared__ int cnt, bits;
    int t = threadIdx.x;
    if (t == 0) { cnt = 0; bits = 0; }
    __syncthreads();
    int c = 0;
    for (int k = t; k < 2048; k += 256) {
        unsigned int w = fv[k];
        unsigned int h0 = w & 0xffffu, h1 = w >> 16;
        unsigned int e0 = (h0 >> 7) & 0xffu, e1 = (h1 >> 7) & 0xffu;
        c += (h0 == 0u || (e0 >= 100u && e0 <= 135u)) ? 1 : 0;
        c += (h1 == 0u || (e1 >= 100u && e1 <= 135u)) ? 1 : 0;
    }
    atomicAdd(&cnt, c);
    int lb = 0;
    for (int k = t; k < mwords; k += 256) {
        unsigned int w = m[k];
        if (w > 1u) lb |= 1;
        if ((k & 1) && w != 0u) lb |= 2;
        unsigned int lo = w & 0xffffu, hi = w >> 16;
        if (!((lo == 0u || lo == 0x3f80u) && (hi == 0u || hi == 0x3f80u))) lb |= 4;
        if (lo == 0x3f80u) lb |= 8;
    }
    if (lb) atomicOr(&bits, lb);
    __syncthreads();
    if (t == 0) {
        int b = bits, f;
        if (!(b & 1))      f = (b & 2) ? 0 : 3;
        else if (!(b & 4)) f = (b & 8) ? 2 : 4;
        else               f = 1;
        flags[0] = f;
        flags[1] = (cnt < 3900) ? 1 : 0;
    }
}

// ---------------- front: build_feat + attn_w transpose + weight packing (one dispatch) ----------------
// grid 2048: [0,512) feat gather; [512,1280) awT transpose; [1280,2048) wc/bias/abf32
__global__ __launch_bounds__(256) void front_kernel(
    const void* __restrict__ fv, const int* __restrict__ x_idx,
    const void* __restrict__ maskp, const int* __restrict__ flags,
    int xstride, int mstride, f16* __restrict__ feat,
    const void* __restrict__ attn_w,
    const void* __restrict__ cls_w, const void* __restrict__ cls_b,
    const void* __restrict__ reg_w, const void* __restrict__ reg_b,
    const void* __restrict__ attn_b,
    f16* __restrict__ awT, f16* __restrict__ wcT,
    float* __restrict__ biasc, float* __restrict__ abf32)
{
    int bid = blockIdx.x;
    int t = threadIdx.x;
    int isf = flags[1], fm = flags[0];
    if (bid < 512) {
        __shared__ f16 sfv[15360];                  // [(c*12+h)*20 + x]
        __shared__ int sx[756];
        __shared__ unsigned char sm[756];
        int b = bid >> 4, n0 = (bid & 15) * 63;
        int rows = min(63, 1000 - n0);
        if (isf) {                                  // f32: 3840 float4
            const float4* src = (const float4*)fv + (long)b * 3840;
            for (int k = t; k < 3840; k += 256) {
                float4 v = src[k];
                f16x4 h; h[0] = (f16)v.x; h[1] = (f16)v.y; h[2] = (f16)v.z; h[3] = (f16)v.w;
                *(f16x4*)&sfv[k * 4] = h;
            }
        } else {                                    // bf16: 1920 uint4
            const uint4* src = (const uint4*)fv + (long)b * 1920;
            for (int k = t; k < 1920; k += 256) {
                uint4 v = src[k];
                unsigned int wv[4] = {v.x, v.y, v.z, v.w};
                f16x8 h;
                #pragma unroll
                for (int j = 0; j < 4; j++) {
                    h[2 * j]     = (f16)__uint_as_float((wv[j] & 0xffffu) << 16);
                    h[2 * j + 1] = (f16)__uint_as_float(wv[j] & 0xffff0000u);
                }
                *(f16x8*)&sfv[k * 8] = h;
            }
        }
        for (int k = t; k < rows * 12; k += 256) {
            int n = k / 12, h = k - n * 12;
            sx[k] = x_idx[(long)(n0 + n) * xstride + h];
            long mb = (long)(n0 + n) * mstride + h;
            int mv;
            if (fm == 0)      mv = ((const int*)maskp)[mb] != 0;
            else if (fm == 1) mv = ((const unsigned char*)maskp)[mb] != 0;
            else if (fm == 2) mv = ((const unsigned short*)maskp)[mb] != 0;
            else if (fm == 3) mv = ((const int*)maskp)[mb * 2] != 0;
            else              mv = ((const unsigned int*)maskp)[mb] != 0;
            sm[k] = (unsigned char)mv;
        }
        __syncthreads();
        for (int q = t; q < rows * 192; q += 256) {
            int n = q / 192, r = q - n * 192;
            int e0 = r * 4;
            f16x4 v;
            #pragma unroll
            for (int j = 0; j < 4; j++) {
                int e = e0 + j;
                int h = e % 12;
                int kk = n * 12 + h;
                v[j] = sm[kk] ? (f16)0.f : sfv[e * 20 + sx[kk]];
            }
            *(f16x4*)(feat + ((long)(b * 1000 + n0 + n)) * 768 + e0) = v;
        }
    } else if (bid < 1280) {
        // attn_w (768 x 999, ld 999) -> awT (1024 x 768, ld 768), rows>=999 zero
        __shared__ f16 tile[32][33];
        int tid = bid - 512;
        int c0 = (tid % 32) * 32, r0 = (tid / 32) * 32;    // c: 0..1023, r: 0..767
        int tx = t & 31, ty = t >> 5;
        #pragma unroll
        for (int i = ty; i < 32; i += 8) {
            int r = r0 + i, c = c0 + tx;
            float v = 0.f;
            if (r < 768 && c < 999) v = ldf(attn_w, (long)r * 999 + c, isf);
            tile[i][tx] = (f16)v;
        }
        __syncthreads();
        #pragma unroll
        for (int i = ty; i < 32; i += 8) {
            int oc = c0 + i, orw = r0 + tx;
            awT[(long)oc * 768 + orw] = tile[tx][i];
        }
    } else {
        int idx = (bid - 1280) * 256 + t;           // 128*1536 = 196608
        if (idx < 128 * 1536) {
            int c = idx / 1536, k = idx - c * 1536;
            float v = 0.f;
            if (c < 2)       v = ldf(cls_w, (long)k * 2 + c, isf);
            else if (c < 75) v = ldf(reg_w, (long)k * 73 + (c - 2), isf);
            wcT[idx] = (f16)v;                       // wcT[c][k], ld 1536
        }
        if (idx < 75)
            biasc[idx] = (idx < 2) ? ldf(cls_b, idx, isf) : ldf(reg_b, idx - 2, isf);
        if (idx < 1024)
            abf32[idx] = (idx < 999) ? ldf(attn_b, idx, isf) : 0.f;
    }
}

// ---------------- transp: feat -> featT per batch, 64x64 tiles, f16x4 both sides ----------------
__global__ __launch_bounds__(256) void transp_kernel(
    const f16* __restrict__ feat, f16* __restrict__ featT)
{
    __shared__ f16 tile[64][68];                    // pad 4: rows spread across banks
    int bid = blockIdx.x;
    int bz = bid / 192;
    int rq = bid - bz * 192;
    int by = rq & 15, bx = rq >> 4;                 // by: n-tile 0..15, bx: d-tile 0..11
    int r0 = by * 64, c0 = bx * 64;
    int t = threadIdx.x;
    int tr = t >> 4, tc = (t & 15) * 4;             // tr 0..15, tc 0..60
    const f16* src = feat + (long)bz * 768000;
    #pragma unroll
    for (int ii = 0; ii < 4; ii++) {
        int r = r0 + ii * 16 + tr;
        f16x4 v = {(f16)0.f, (f16)0.f, (f16)0.f, (f16)0.f};
        if (r < 1000) v = *(const f16x4*)(src + (long)r * 768 + c0 + tc);
        *(f16x4*)&tile[ii * 16 + tr][tc] = v;
    }
    __syncthreads();
    f16* dst = featT + (long)bz * 786432;
    #pragma unroll
    for (int ii = 0; ii < 4; ii++) {
        int d = ii * 16 + tr;                       // local d index
        f16x4 v;
        #pragma unroll
        for (int j = 0; j < 4; j++) v[j] = tile[tc + j][d];
        *(f16x4*)(dst + (long)(c0 + d) * 1024 + r0 + tc) = v;
    }
}

// ---------------- post: softmax-scatter, vectorized output-position stores ----------------
// Each block owns one row (b,i) of logits (1024 wide, 999 real). Output row:
// out[p] = 0 (p==i or p>=1000); e[p]/sum (p<i); e[p-1]/sum (p>i). Only the
// "all p > i" case needs a neighbor value (thread t-1's e[3]) -> tiny LDS relay.
__global__ __launch_bounds__(256) void post_kernel(
    f16* __restrict__ buf, const float* __restrict__ abf32)
{
    int bid = blockIdx.x;
    int t = threadIdx.x;
    int i = bid % 1000, b = bid / 1000;
    f16* row = buf + ((long)(b * 1000 + i)) * 1024;
    __shared__ float red[8];
    __shared__ float epv[256];
    int k0 = t * 4;
    f16x4 rv = *(const f16x4*)(row + k0);            // all reads before any write
    float4 ab = *(const float4*)(abf32 + k0);
    float abv[4] = {ab.x, ab.y, ab.z, ab.w};
    float v[4];
    float lmax = -3.4e38f;
    #pragma unroll
    for (int j = 0; j < 4; j++) {
        int k = k0 + j;
        float x = (k < 999) ? (float)rv[j] + abv[j] : -3.4e38f;
        v[j] = x;
        lmax = fmaxf(lmax, x);
    }
    #pragma unroll
    for (int o = 32; o > 0; o >>= 1) lmax = fmaxf(lmax, __shfl_down(lmax, o, 64));
    if ((t & 63) == 0) red[t >> 6] = lmax;
    __syncthreads();
    float gmax = fmaxf(fmaxf(red[0], red[1]), fmaxf(red[2], red[3]));
    float e[4];
    float lsum = 0.f;
    #pragma unroll
    for (int j = 0; j < 4; j++) {
        int k = k0 + j;
        float x = (k < 999) ? __expf(v[j] - gmax) : 0.f;
        e[j] = x;
        lsum += x;
    }
    epv[t] = e[3];
    #pragma unroll
    for (int o = 32; o > 0; o >>= 1) lsum += __shfl_down(lsum, o, 64);
    if ((t & 63) == 0) red[4 + (t >> 6)] = lsum;
    __syncthreads();                                 // also covers epv writes
    float inv = 1.f / (red[4] + red[5] + red[6] + red[7]);
    f16x4 outv;
    if (k0 >= 1000) {                                // tail: all zeros
        #pragma unroll
        for (int j = 0; j < 4; j++) outv[j] = (f16)0.f;
    } else if (k0 + 3 < i) {                         // all p < i: own e's
        #pragma unroll
        for (int j = 0; j < 4; j++) outv[j] = (f16)(e[j] * inv);
    } else if (k0 > i) {                             // all p > i: shift by one
        float ep = epv[t - 1];                       // t>=1 guaranteed (k0>i>=0)
        outv[0] = (f16)(ep * inv);
        #pragma unroll
        for (int j = 1; j < 4; j++) outv[j] = (f16)(e[j - 1] * inv);
    } else {                                         // straddle: i in [k0, k0+3]
        #pragma unroll
        for (int j = 0; j < 4; j++) {
            int p = k0 + j;
            float s = (p == i) ? 0.f : ((p < i) ? e[j] : e[j - 1 < 0 ? 0 : j - 1]);
            if (p > i) s = e[j - 1];                 // p>i implies j>=1 here
            outv[j] = (f16)(s * inv);
        }
    }
    *(f16x4*)(row + k0) = outv;
}

// ---------------- 8-phase 256x256 MFMA GEMM (T2+T3+T4+T5) ----------------
// 512 thr = 8 waves (2M x 4N), per-wave 128x64 out, BK=64, dbuf LDS 128 KiB.
// Per iteration: 2 K-tiles, 8 phases; each phase: {ds_read frags | stage 1
// half-tile gl2lds} -> s_barrier -> lgkmcnt(0) -> setprio(1) 16 MFMA setprio(0)
// -> [vmcnt(4) at phases 3,7] -> s_barrier.
#define SB8   __builtin_amdgcn_sched_barrier(0)
#define BAR8  __builtin_amdgcn_s_barrier()
#define LGKM0 do { asm volatile("s_waitcnt lgkmcnt(0)" ::: "memory"); __builtin_amdgcn_sched_barrier(0); } while (0)
#define VM4   asm volatile("s_waitcnt vmcnt(4)" ::: "memory")

__global__ __launch_bounds__(512, 2) void gemm8p_kernel(
    const f16* __restrict__ A, int lda,
    const f16* __restrict__ Bt, int ldb,
    f16* __restrict__ C, int ldc,
    int M, int MT, int NT, int KT,
    long sA, long sB, long sC)
{
    __shared__ __align__(16) f16 As[2][16384];
    __shared__ __align__(16) f16 Bs[2][16384];
    int t = threadIdx.x;
    int nwg = gridDim.x;
    int orig = blockIdx.x;
    int xcd = orig & 7, lin = orig >> 3;
    int q8 = nwg >> 3, r8 = nwg & 7;                 // bijective XCD swizzle (m204)
    int wgid = (xcd < r8 ? xcd * (q8 + 1) : r8 * (q8 + 1) + (xcd - r8) * q8) + lin;
    int per_b = MT * NT;
    int bz = wgid / per_b;
    int rem = wgid - bz * per_b;
    int mt = rem / NT, nt = rem - mt * NT;
    int m0 = mt * 256, n0 = nt * 256;
    A  += (long)bz * sA;
    Bt += (long)bz * sB;
    C  += (long)bz * sC;
    int w = t >> 6, lane = t & 63;
    int wm = (w >> 2) * 128, wn = (w & 3) * 64;
    int lr = lane & 15, lq = lane >> 4;
    int row0 = t >> 3, slot = t & 7;
    int csw = slot ^ (row0 & 7);                     // pre-swizzled global source

    f32x4 acc[8][4];
    const f32x4 z4 = {0.f, 0.f, 0.f, 0.f};
    #pragma unroll
    for (int i = 0; i < 8; i++)
        #pragma unroll
        for (int j = 0; j < 4; j++) acc[i][j] = z4;

    f16x8 a_[2][2], b_[4][2];

// stage half h (128 rows, 2x gl2lds) of tile kt into buf; clamp kt for tail
#define STAGE_A8(kt, h, buf) do { \
    int ktc = (kt) < KT ? (kt) : KT - 1; \
    const f16* gp = A + (long)(m0 + (h) * 128 + row0) * lda + ktc * 64 + csw * 8; \
    gl2lds16(gp,                  &As[buf][(h) * 8192 + w * 512]); \
    gl2lds16(gp + 64 * (long)lda, &As[buf][(h) * 8192 + 4096 + w * 512]); \
} while (0)
#define STAGE_B8(kt, h, buf) do { \
    int ktc = (kt) < KT ? (kt) : KT - 1; \
    const f16* gp = Bt + (long)(n0 + (h) * 128 + row0) * ldb + ktc * 64 + csw * 8; \
    gl2lds16(gp,                  &Bs[buf][(h) * 8192 + w * 512]); \
    gl2lds16(gp + 64 * (long)ldb, &Bs[buf][(h) * 8192 + 4096 + w * 512]); \
} while (0)
#define RD_B8(buf) { \
    _Pragma("unroll") for (int n = 0; n < 4; n++) { \
        int r = wn + n * 16 + lr; int rb = r * 64; int x7 = r & 7; \
        _Pragma("unroll") for (int ks = 0; ks < 2; ks++) { \
            int cc = (lq + ks * 4) ^ x7; \
            b_[n][ks] = *(const f16x8*)&Bs[buf][rb + cc * 8]; } } }
#define RD_A8(q, buf) { \
    _Pragma("unroll") for (int m2 = 0; m2 < 2; m2++) { \
        int r = wm + ((q) * 2 + m2) * 16 + lr; int rb = r * 64; int x7 = r & 7; \
        _Pragma("unroll") for (int ks = 0; ks < 2; ks++) { \
            int cc = (lq + ks * 4) ^ x7; \
            a_[m2][ks] = *(const f16x8*)&As[buf][rb + cc * 8]; } } }
#define MFMA16(q) { \
    __builtin_amdgcn_s_setprio(1); \
    _Pragma("unroll") for (int ks = 0; ks < 2; ks++) \
    _Pragma("unroll") for (int m2 = 0; m2 < 2; m2++) \
    _Pragma("unroll") for (int n = 0; n < 4; n++) \
        acc[(q) * 2 + m2][n] = __builtin_amdgcn_mfma_f32_16x16x32_f16( \
            a_[m2][ks], b_[n][ks], acc[(q) * 2 + m2][n], 0, 0, 0); \
    __builtin_amdgcn_s_setprio(0); }

    // prologue: B(0),A(0) -> buf0; B(1) -> buf1; wait oldest 8, keep B(1) in flight
    STAGE_B8(0, 0, 0); STAGE_B8(0, 1, 0);
    STAGE_A8(0, 0, 0); STAGE_A8(0, 1, 0);
    STAGE_B8(1, 0, 1); STAGE_B8(1, 1, 1);
    VM4;
    BAR8;

    int NIT = KT >> 1;
    for (int it = 0; it < NIT; it++) {
        int t0 = 2 * it, t1 = t0 + 1;
        // phase 0: tile t0 (buf0): all B frags + A quad 0 | stage A0(t1)->buf1
        SB8; RD_B8(0); RD_A8(0, 0); STAGE_A8(t1, 0, 1);
        BAR8; LGKM0; MFMA16(0); BAR8;
        // phase 1
        SB8; RD_A8(1, 0); STAGE_A8(t1, 1, 1);
        BAR8; LGKM0; MFMA16(1); BAR8;
        // phase 2: Bs[0] consumed in phase 0 -> stage B(t0+2)
        SB8; RD_A8(2, 0); STAGE_B8(t0 + 2, 0, 0);
        BAR8; LGKM0; MFMA16(2); BAR8;
        // phase 3: counted wait: A(t1)+B(t1) must be the oldest 8 of 12
        SB8; RD_A8(3, 0); STAGE_B8(t0 + 2, 1, 0);
        BAR8; LGKM0; MFMA16(3); VM4; BAR8;
        // phase 4: tile t1 (buf1); As[0] consumed end of phase 3 -> stage A(t0+2)
        SB8; RD_B8(1); RD_A8(0, 1); STAGE_A8(t0 + 2, 0, 0);
        BAR8; LGKM0; MFMA16(0); BAR8;
        // phase 5
        SB8; RD_A8(1, 1); STAGE_A8(t0 + 2, 1, 0);
        BAR8; LGKM0; MFMA16(1); BAR8;
        // phase 6: Bs[1] consumed in phase 4 -> stage B(t1+2)
        SB8; RD_A8(2, 1); STAGE_B8(t1 + 2, 0, 1);
        BAR8; LGKM0; MFMA16(2); BAR8;
        // phase 7: counted wait: A(t0+2)+B(t0+2) oldest 8 of 12
        SB8; RD_A8(3, 1); STAGE_B8(t1 + 2, 1, 1);
        BAR8; LGKM0; MFMA16(3); VM4; BAR8;
    }

    // epilogue: C/D layout col=lane&15, row=(lane>>4)*4+reg
    #pragma unroll
    for (int m = 0; m < 8; m++)
        #pragma unroll
        for (int n = 0; n < 4; n++)
            #pragma unroll
            for (int r = 0; r < 4; r++) {
                int gm = m0 + wm + m * 16 + lq * 4 + r;
                int gn = n0 + wn + n * 16 + lr;
                if (gm < M) C[(long)gm * ldc + gn] = (f16)acc[m][n][r];
            }
#undef STAGE_A8
#undef STAGE_B8
#undef RD_B8
#undef RD_A8
#undef MFMA16
}

// ---------------- MFMA GEMM (legacy paths: GEMM3 BG + non-bigws fallback) ----------------
enum { OUT_F16 = 0, OUT_FINAL = 1 };

template<int MODE, bool CAT, bool BKM, int TM, int TN, int BK, int SWZ, bool BG>
__global__ __launch_bounds__(256, 2) void gemm_kernel(
    const f16* __restrict__ A, const f16* __restrict__ A2, int lda,
    const f16* __restrict__ Bt, int ldb,
    void* __restrict__ Cout, int ldc,
    int M, int Nc, int K,
    long sA, long sB, long sC,
    const float* __restrict__ bias, const void* __restrict__ anchors,
    const int* __restrict__ flags)
{
    int t = threadIdx.x;
    int bx, by, bz;
    if constexpr (SWZ == 2) {          // flat grid: ngroups m-groups x 4 n-blocks
        int bid = blockIdx.x;
        int xcd = bid & 7, s = bid >> 3;
        int g = xcd + 8 * (s >> 2);                  // XCD owns groups g == xcd (mod 8)
        if (g >= (M + TM - 1) / TM) return;
        by = g; bx = s & 3; bz = 0;
    } else if constexpr (SWZ == 3) {   // grid 768 flat: 8 XCD x 4 batches x (8m x 3n)
        int bid = blockIdx.x;
        int xcd = bid & 7, s = bid >> 3;             // s in [0,96)
        bz = xcd * 4 + s / 24;
        int wv = s % 24;
        by = wv / 3; bx = wv - by * 3;
    } else { bx = blockIdx.x; by = blockIdx.y; bz = blockIdx.z; }

    int m0 = by * TM, n0 = bx * TN;
    int z = bz;
    A  += (long)z * sA;
    if (CAT) A2 += (long)z * sA;
    Bt += (long)z * sB;
    int w = t >> 6, lane = t & 63;
    constexpr int NJ = (TM == 128 && TN == 256) ? 8 : ((TN == 256) ? 4 : ((TM == 128) ? 4 : 2));
    int wm = (TM == 128) ? (w & 1) * 64 : 0;
    int wn;
    if constexpr (TM == 128 && TN == 256) wn = (w >> 1) * 128;
    else if constexpr (TN == 256)         wn = w * 64;
    else if constexpr (TM == 128)         wn = (w >> 1) * 64;
    else                                  wn = w * 32;

    int lr = lane & 15, lq = lane >> 4;

    const f32x4 zero4 = {0.f, 0.f, 0.f, 0.f};
    f32x4 acc[4][NJ];
    #pragma unroll
    for (int i = 0; i < 4; i++)
        #pragma unroll
        for (int j = 0; j < NJ; j++) acc[i][j] = zero4;

    if constexpr (BG) {
        // A staged to LDS; B fragments straight from global (B must be L2-hot & row-padded)
        constexpr int CH  = BK / 8;
        constexpr int AI  = TM * BK / 2048;
        constexpr int RPO = 2048 / BK;
        __shared__ __align__(16) f16 As[TM * BK];
        int row0 = t / CH, slot = t % CH;
        int csw = slot ^ (row0 & (CH - 1));
        long aoffB = (long)(m0 + row0) * lda + csw * 8;
        for (int k0 = 0; k0 < K; k0 += BK) {
            const f16* Ak = A; int kk = k0;
            if (CAT && k0 >= 768) { Ak = A2; kk = k0 - 768; }
            __syncthreads();
            #pragma unroll
            for (int i = 0; i < AI; i++)
                gl2lds16(Ak + aoffB + (long)(i * RPO) * lda + kk, &As[i * 2048 + w * 512]);
            f16x8 ball[BK / 32][NJ];
            #pragma unroll
            for (int ks = 0; ks < BK / 32; ks++)
                #pragma unroll
                for (int j = 0; j < NJ; j++) {
                    int r = wn + j * 16 + lr;
                    ball[ks][j] = *(const f16x8*)(Bt + (long)r * ldb + k0 + (ks * 4 + lq) * 8);
                }
            __syncthreads();
            #pragma unroll
            for (int ks = 0; ks < BK / 32; ks++) {
                f16x8 af[4];
                #pragma unroll
                for (int i = 0; i < 4; i++) {
                    int r = wm + i * 16 + lr;
                    int cc = (lq + ks * 4) ^ (r & (CH - 1));
                    af[i] = *(const f16x8*)&As[r * BK + cc * 8];
                }
                #pragma unroll
                for (int i = 0; i < 4; i++)
                    #pragma unroll
                    for (int j = 0; j < NJ; j++)
                        acc[i][j] = __builtin_amdgcn_mfma_f32_16x16x32_f16(af[i], ball[ks][j], acc[i][j], 0, 0, 0);
            }
        }
    } else if constexpr (!BKM) {
        constexpr int CH  = BK / 8;                  // 16B chunks per row
        constexpr int AI  = TM * BK / 2048;          // staging ops (2048 elems each)
        constexpr int BI  = TN * BK / 2048;
        constexpr int RPO = 2048 / BK;               // rows per staging op
        __shared__ __align__(16) f16 As[TM * BK];
        __shared__ __align__(16) f16 Bs[TN * BK];
        int row0 = t / CH, slot = t % CH;
        int csw = slot ^ (row0 & (CH - 1));
        long aoffB = (long)(m0 + row0) * lda + csw * 8;
        long boffB = (long)(n0 + row0) * ldb + csw * 8;
        for (int k0 = 0; k0 < K; k0 += BK) {
            const f16* Ak = A; int kk = k0;
            if (CAT && k0 >= 768) { Ak = A2; kk = k0 - 768; }
            __syncthreads();
            #pragma unroll
            for (int i = 0; i < AI; i++)
                gl2lds16(Ak + aoffB + (long)(i * RPO) * lda + kk, &As[i * 2048 + w * 512]);
            #pragma unroll
            for (int i = 0; i < BI; i++)
                gl2lds16(Bt + boffB + (long)(i * RPO) * ldb + k0, &Bs[i * 2048 + w * 512]);
            __syncthreads();                         // drains vmcnt before barrier
            #pragma unroll
            for (int ks = 0; ks < BK / 32; ks++) {
                f16x8 af[4], bfr[NJ];
                #pragma unroll
                for (int i = 0; i < 4; i++) {
                    int r = wm + i * 16 + lr;
                    int cc = (lq + ks * 4) ^ (r & (CH - 1));
                    af[i] = *(const f16x8*)&As[r * BK + cc * 8];
                }
                #pragma unroll
                for (int j = 0; j < NJ; j++) {
                    int r = wn + j * 16 + lr;
                    int cc = (lq + ks * 4) ^ (r & (CH - 1));
                    bfr[j] = *(const f16x8*)&Bs[r * BK + cc * 8];
                }
                #pragma unroll
                for (int i = 0; i < 4; i++)
                    #pragma unroll
                    for (int j = 0; j < NJ; j++)
                        acc[i][j] = __builtin_amdgcn_mfma_f32_16x16x32_f16(af[i], bfr[j], acc[i][j], 0, 0, 0);
            }
        }
    } else {
        __shared__ __align__(16) f16 As[128 * 40];
        __shared__ __align__(16) f16 Bs[32 * 132];
        const f16x8 zero8 = {(f16)0, (f16)0, (f16)0, (f16)0, (f16)0, (f16)0, (f16)0, (f16)0};
        const f16x4 zero4h = {(f16)0, (f16)0, (f16)0, (f16)0};
        for (int k0 = 0; k0 < K; k0 += 32) {
            __syncthreads();
            #pragma unroll
            for (int i = 0; i < 2; i++) {
                int q = t + i * 256;
                { int row = q >> 2, kc = (q & 3) * 8;
                  f16x8 av = zero8;
                  if ((m0 + row) < M && (k0 + kc) < K)
                      av = *(const f16x8*)(A + (long)(m0 + row) * lda + k0 + kc);
                  *(f16x8*)&As[row * 40 + kc] = av; }
                { int kr = q >> 4, nc = (q & 15) * 8;
                  f16x4 b0 = zero4h, b1 = zero4h;
                  if ((k0 + kr) < K && (n0 + nc) < Nc) {
                      const f16* p2 = Bt + (long)(k0 + kr) * ldb + n0 + nc;
                      b0 = *(const f16x4*)p2;
                      b1 = *(const f16x4*)(p2 + 4);
                  }
                  *(f16x4*)&Bs[kr * 132 + nc]     = b0;
                  *(f16x4*)&Bs[kr * 132 + nc + 4] = b1; }
            }
            __syncthreads();
            f16x8 af[4], bfr[NJ];
            #pragma unroll
            for (int i = 0; i < 4; i++)
                af[i] = *(const f16x8*)&As[(wm + i * 16 + lr) * 40 + lq * 8];
            #pragma unroll
            for (int j = 0; j < NJ; j++)
                #pragma unroll
                for (int jj = 0; jj < 8; jj++)
                    bfr[j][jj] = Bs[(lq * 8 + jj) * 132 + wn + j * 16 + lr];
            #pragma unroll
            for (int i = 0; i < 4; i++)
                #pragma unroll
                for (int j = 0; j < NJ; j++)
                    acc[i][j] = __builtin_amdgcn_mfma_f32_16x16x32_f16(af[i], bfr[j], acc[i][j], 0, 0, 0);
        }
    }

    int isf = (MODE == OUT_FINAL) ? flags[1] : 0;
    #pragma unroll
    for (int i = 0; i < 4; i++) {
        #pragma unroll
        for (int j = 0; j < NJ; j++) {
            #pragma unroll
            for (int r = 0; r < 4; r++) {
                int gm = m0 + wm + i * 16 + lq * 4 + r;   // C/D: row = quad*4+reg
                int gn = n0 + wn + j * 16 + lr;           //      col = lane&15
                if (MODE == OUT_F16) {
                    if (gm < M && gn < Nc)
                        ((f16*)Cout)[(long)z * sC + (long)gm * ldc + gn] = (f16)acc[i][j][r];
                } else {
                    if (gn < Nc) {                         // Nc=75 real cols
                        float v = acc[i][j][r] + bias[gn];
                        int oc = (gn < 2) ? gn : gn + 2;   // skip anchor cols 2,3
                        if (gn >= 2) v += ldf(anchors, (long)(gm % 1000) * 77 + oc, isf);
                        stf(Cout, (long)gm * 77 + oc, isf, v);
                    } else if (gn < 77) {                  // wasted lanes fill anchor cols 2,3
                        int oc = gn - 73;                  // 75->2, 76->3
                        stf(Cout, (long)gm * 77 + oc, isf,
                            ldf(anchors, (long)(gm % 1000) * 77 + oc, isf));
                    }
                }
            }
        }
    }
}

extern "C" void kernel_launch(void* const* d_in, const int* in_sizes, int n_in,
                              void* d_out, int out_size, void* d_ws, size_t ws_size,
                              hipStream_t stream)
{
    const void* fv      = d_in[0];
    const void* attn_w  = d_in[1];
    const void* attn_b  = d_in[2];
    const void* cls_w   = d_in[3];
    const void* cls_b   = d_in[4];
    const void* reg_w   = d_in[5];
    const void* reg_b   = d_in[6];
    const void* anchors = d_in[7];
    const int*  x_idx   = (const int*)d_in[10];
    const void* maskp   = d_in[11];
    int xstride = (in_sizes[10] < 768000) ? 12 : 768;   // un-broadcast fallback
    int mstride = (in_sizes[11] < 768000) ? 12 : 768;
    int mwords  = in_sizes[11] / 4;                      // int8 worst case, stay in bounds
    if (mwords > 4096) mwords = 4096;

    char* ws = (char*)d_ws;
    f16*   logits = (f16*)(ws + OFF_LOGITS);
    f16*   feat   = (f16*)(ws + OFF_FEAT);
    f16*   attf   = (f16*)(ws + OFF_ATTF);
    f16*   awT    = (f16*)(ws + OFF_AWT);
    f16*   wcT    = (f16*)(ws + OFF_WCT);
    float* biasc  = (float*)(ws + OFF_BIAS);
    float* abf32  = (float*)(ws + OFF_AB);
    int*   flags  = (int*)(ws + OFF_FLAG);
    f16*   featT  = (f16*)(ws + OFF_FEATT);
    bool bigws = ws_size >= (size_t)NEED_A;

    detect_kernel<<<dim3(1), dim3(256), 0, stream>>>(
        (const unsigned int*)fv, (const unsigned int*)maskp, mwords, flags);
    front_kernel<<<dim3(2048), dim3(256), 0, stream>>>(
        fv, x_idx, maskp, flags, xstride, mstride, feat,
        attn_w, cls_w, cls_b, reg_w, reg_b, attn_b, awT, wcT, biasc, abf32);

    // transpose feat -> featT (vectorized 64x64 tiles); only needs feat
    if (bigws)
        transp_kernel<<<dim3(6144), dim3(256), 0, stream>>>(feat, featT);

    // GEMM1: logits = feat @ attn_w  (M=32000, N=1024 padded, K=768), 8-phase 256^2
    gemm8p_kernel<<<dim3(500), dim3(512), 0, stream>>>(
        feat, 768, awT, 768, logits, 1024, 32000, 125, 4, 12, 0L, 0L, 0L);
    // softmax-scatter (vectorized stores), one block per row
    post_kernel<<<dim3(32000), dim3(256), 0, stream>>>(logits, abf32);
    // GEMM2 (batched): att_feat = S @ feat  (M=1000, N=768, K=1024 padded, 32 batches)
    if (bigws) {
        gemm8p_kernel<<<dim3(384), dim3(512), 0, stream>>>(
            logits, 1024, featT, 1024, attf, 768, 1000, 4, 3, 16,
            1024000L, 786432L, 768000L);
    } else {
        gemm_kernel<OUT_F16, false, true, 128, 128, 32, 0, false><<<dim3(6, 8, 32), dim3(256), 0, stream>>>(
            logits, nullptr, 1024, feat, 768, attf, 768, 1000, 768, 1000,
            1024000L, 768000L, 768000L, nullptr, nullptr, flags);
    }
    // GEMM3: out = [att_feat | feat] @ Wc, fused epilogue; lean BG path (B=wcT from L2),
    // A-only LDS (16 KB), BK=128, TM=64/TN=128 -> 500 blocks, ~3 blocks/CU
    gemm_kernel<OUT_FINAL, true, false, 64, 128, 128, 0, true><<<dim3(1, 500, 1), dim3(256), 0, stream>>>(
        attf, feat, 768, wcT, 1536, d_out, 77, 32000, 75, 1536, 0, 0, 0,
        biasc, anchors, flags);
}

// Round 6
// 292.970 us; speedup vs baseline: 1.2493x; 1.1561x over previous
//
#include <hip/hip_runtime.h>
#include <hip/hip_bf16.h>

typedef _Float16 f16;
typedef _Float16 f16x4 __attribute__((ext_vector_type(4)));
typedef _Float16 f16x8 __attribute__((ext_vector_type(8)));
typedef float    f32x4 __attribute__((ext_vector_type(4)));

static __device__ __forceinline__ float bf2f(__hip_bfloat16 x) { return __bfloat162float(x); }
// dual-dtype float load/store: f32flag=1 -> float*, else bf16*
static __device__ __forceinline__ float ldf(const void* p, long i, int f32flag) {
    return f32flag ? ((const float*)p)[i] : bf2f(((const __hip_bfloat16*)p)[i]);
}
static __device__ __forceinline__ void stf(void* p, long i, int f32flag, float v) {
    if (f32flag) ((float*)p)[i] = v;
    else ((__hip_bfloat16*)p)[i] = __float2bfloat16(v);
}
// async global->LDS, 16B per lane; LDS dest is wave-uniform base + lane*16
static __device__ __forceinline__ void gl2lds16(const f16* g, f16* l) {
    __builtin_amdgcn_global_load_lds(
        (const __attribute__((address_space(1))) unsigned int*)(const void*)g,
        (__attribute__((address_space(3))) unsigned int*)(void*)l, 16, 0, 0);
}

// ---------------- workspace layout (bytes) ----------------
// Re-associated pipeline: att_feat is never materialized.
//   F12 = feat @ [Wc1|Wc2]  (32000 x 256, F1 = cols 0..127, F2 = cols 128..255)
//   out = S @ F1 + F2 + bias + anchors
#define OFF_LOGITS 0L                               // S/logits: 32000 x 1024 f16
#define SZ_LOGITS  (32000L * 1024 * 2)
#define OFF_FEAT   (OFF_LOGITS + SZ_LOGITS)         // feat: 32000 x 768 f16
#define SZ_FEAT    (32000L * 768 * 2)
#define OFF_F12    (OFF_FEAT + SZ_FEAT)             // F12: 32000 x 256 f16
#define SZ_F12     (32000L * 256 * 2)
#define OFF_AWT    (OFF_F12 + SZ_F12)               // attn_w^T: 1024 x 768 f16 (rows>=999 zero)
#define SZ_AWT     (1024L * 768 * 2)
#define OFF_WCT    (OFF_AWT + SZ_AWT)               // Wc2^T: 256 x 768 f16 (c>=75-cols zero)
#define SZ_WCT     (256L * 768 * 2)
#define OFF_BIAS   (OFF_WCT + SZ_WCT)               // f32[128]
#define OFF_AB     (OFF_BIAS + 512)                 // attn_b as f32[1024]
#define OFF_FLAG   (OFF_AB + 4096)                  // int flags[2]
#define OFF_F1T    (OFF_FLAG + 64)                  // F1^T per batch: 32 x 128 x 1024 f16
#define SZ_F1T     (32L * 128 * 1024 * 2)
#define NEED_A     (OFF_F1T + SZ_F1T)               // ~141 MB

// ---------------- detection (cheap sampling) ----------------
__global__ void detect_kernel(const unsigned int* __restrict__ fv,
                              const unsigned int* __restrict__ m,
                              int mwords, int* __restrict__ flags)
{
    __shared__ int cnt, bits;
    int t = threadIdx.x;
    if (t == 0) { cnt = 0; bits = 0; }
    __syncthreads();
    int c = 0;
    for (int k = t; k < 2048; k += 256) {
        unsigned int w = fv[k];
        unsigned int h0 = w & 0xffffu, h1 = w >> 16;
        unsigned int e0 = (h0 >> 7) & 0xffu, e1 = (h1 >> 7) & 0xffu;
        c += (h0 == 0u || (e0 >= 100u && e0 <= 135u)) ? 1 : 0;
        c += (h1 == 0u || (e1 >= 100u && e1 <= 135u)) ? 1 : 0;
    }
    atomicAdd(&cnt, c);
    int lb = 0;
    for (int k = t; k < mwords; k += 256) {
        unsigned int w = m[k];
        if (w > 1u) lb |= 1;
        if ((k & 1) && w != 0u) lb |= 2;
        unsigned int lo = w & 0xffffu, hi = w >> 16;
        if (!((lo == 0u || lo == 0x3f80u) && (hi == 0u || hi == 0x3f80u))) lb |= 4;
        if (lo == 0x3f80u) lb |= 8;
    }
    if (lb) atomicOr(&bits, lb);
    __syncthreads();
    if (t == 0) {
        int b = bits, f;
        if (!(b & 1))      f = (b & 2) ? 0 : 3;
        else if (!(b & 4)) f = (b & 8) ? 2 : 4;
        else               f = 1;
        flags[0] = f;
        flags[1] = (cnt < 3900) ? 1 : 0;
    }
}

// ---------------- front: build_feat + attn_w transpose + weight packing (one dispatch) ----------------
// grid 2048: [0,512) feat gather; [512,1280) awT transpose; [1280,2048) wcT2/bias/abf32
__global__ __launch_bounds__(256) void front_kernel(
    const void* __restrict__ fv, const int* __restrict__ x_idx,
    const void* __restrict__ maskp, const int* __restrict__ flags,
    int xstride, int mstride, f16* __restrict__ feat,
    const void* __restrict__ attn_w,
    const void* __restrict__ cls_w, const void* __restrict__ cls_b,
    const void* __restrict__ reg_w, const void* __restrict__ reg_b,
    const void* __restrict__ attn_b,
    f16* __restrict__ awT, f16* __restrict__ wcT,
    float* __restrict__ biasc, float* __restrict__ abf32)
{
    int bid = blockIdx.x;
    int t = threadIdx.x;
    int isf = flags[1], fm = flags[0];
    if (bid < 512) {
        __shared__ f16 sfv[15360];                  // [(c*12+h)*20 + x]
        __shared__ int sx[756];
        __shared__ unsigned char sm[756];
        int b = bid >> 4, n0 = (bid & 15) * 63;
        int rows = min(63, 1000 - n0);
        if (isf) {                                  // f32: 3840 float4
            const float4* src = (const float4*)fv + (long)b * 3840;
            for (int k = t; k < 3840; k += 256) {
                float4 v = src[k];
                f16x4 h; h[0] = (f16)v.x; h[1] = (f16)v.y; h[2] = (f16)v.z; h[3] = (f16)v.w;
                *(f16x4*)&sfv[k * 4] = h;
            }
        } else {                                    // bf16: 1920 uint4
            const uint4* src = (const uint4*)fv + (long)b * 1920;
            for (int k = t; k < 1920; k += 256) {
                uint4 v = src[k];
                unsigned int wv[4] = {v.x, v.y, v.z, v.w};
                f16x8 h;
                #pragma unroll
                for (int j = 0; j < 4; j++) {
                    h[2 * j]     = (f16)__uint_as_float((wv[j] & 0xffffu) << 16);
                    h[2 * j + 1] = (f16)__uint_as_float(wv[j] & 0xffff0000u);
                }
                *(f16x8*)&sfv[k * 8] = h;
            }
        }
        for (int k = t; k < rows * 12; k += 256) {
            int n = k / 12, h = k - n * 12;
            sx[k] = x_idx[(long)(n0 + n) * xstride + h];
            long mb = (long)(n0 + n) * mstride + h;
            int mv;
            if (fm == 0)      mv = ((const int*)maskp)[mb] != 0;
            else if (fm == 1) mv = ((const unsigned char*)maskp)[mb] != 0;
            else if (fm == 2) mv = ((const unsigned short*)maskp)[mb] != 0;
            else if (fm == 3) mv = ((const int*)maskp)[mb * 2] != 0;
            else              mv = ((const unsigned int*)maskp)[mb] != 0;
            sm[k] = (unsigned char)mv;
        }
        __syncthreads();
        for (int q = t; q < rows * 192; q += 256) {
            int n = q / 192, r = q - n * 192;
            int e0 = r * 4;
            f16x4 v;
            #pragma unroll
            for (int j = 0; j < 4; j++) {
                int e = e0 + j;
                int h = e % 12;
                int kk = n * 12 + h;
                v[j] = sm[kk] ? (f16)0.f : sfv[e * 20 + sx[kk]];
            }
            *(f16x4*)(feat + ((long)(b * 1000 + n0 + n)) * 768 + e0) = v;
        }
    } else if (bid < 1280) {
        // attn_w (768 x 999, ld 999) -> awT (1024 x 768, ld 768), rows>=999 zero
        __shared__ f16 tile[32][33];
        int tid = bid - 512;
        int c0 = (tid % 32) * 32, r0 = (tid / 32) * 32;    // c: 0..1023, r: 0..767
        int tx = t & 31, ty = t >> 5;
        #pragma unroll
        for (int i = ty; i < 32; i += 8) {
            int r = r0 + i, c = c0 + tx;
            float v = 0.f;
            if (r < 768 && c < 999) v = ldf(attn_w, (long)r * 999 + c, isf);
            tile[i][tx] = (f16)v;
        }
        __syncthreads();
        #pragma unroll
        for (int i = ty; i < 32; i += 8) {
            int oc = c0 + i, orw = r0 + tx;
            awT[(long)oc * 768 + orw] = tile[tx][i];
        }
    } else {
        // wcT2 [256 x 768]: row c<128 -> Wc[k][c] (att part, W rows 0..767);
        //                   row c>=128 -> Wc[768+k][c-128] (feat part)
        int idx = (bid - 1280) * 256 + t;           // 256*768 = 196608
        if (idx < 256 * 768) {
            int c = idx / 768, k = idx - c * 768;
            int wrow = (c < 128) ? k : 768 + k;
            int wcol = (c < 128) ? c : c - 128;
            float v = 0.f;
            if (wcol < 2)       v = ldf(cls_w, (long)wrow * 2 + wcol, isf);
            else if (wcol < 75) v = ldf(reg_w, (long)wrow * 73 + (wcol - 2), isf);
            wcT[idx] = (f16)v;                       // wcT2[c][k], ld 768
        }
        if (idx < 75)
            biasc[idx] = (idx < 2) ? ldf(cls_b, idx, isf) : ldf(reg_b, idx - 2, isf);
        if (idx < 1024)
            abf32[idx] = (idx < 999) ? ldf(attn_b, idx, isf) : 0.f;
    }
}

// ---------------- transpF1: F12 cols 0..127 -> F1T per batch (128 x 1024) ----------------
__global__ __launch_bounds__(256) void transpf1_kernel(
    const f16* __restrict__ F12, f16* __restrict__ F1T)
{
    __shared__ f16 tile[64][68];
    int bid = blockIdx.x;
    int bz = bid >> 5;                              // 32 tiles per batch
    int rq = bid & 31;
    int by = rq & 15, bx = rq >> 4;                 // by: r-tile 0..15, bx: c-tile 0..1
    int r0 = by * 64, c0 = bx * 64;
    int t = threadIdx.x;
    int tr = t >> 4, tc = (t & 15) * 4;
    const f16* src = F12 + (long)bz * 1000 * 256;
    #pragma unroll
    for (int ii = 0; ii < 4; ii++) {
        int r = r0 + ii * 16 + tr;
        f16x4 v = {(f16)0.f, (f16)0.f, (f16)0.f, (f16)0.f};
        if (r < 1000) v = *(const f16x4*)(src + (long)r * 256 + c0 + tc);
        *(f16x4*)&tile[ii * 16 + tr][tc] = v;
    }
    __syncthreads();
    f16* dst = F1T + (long)bz * 131072;
    #pragma unroll
    for (int ii = 0; ii < 4; ii++) {
        int d = ii * 16 + tr;
        f16x4 v;
        #pragma unroll
        for (int j = 0; j < 4; j++) v[j] = tile[tc + j][d];
        *(f16x4*)(dst + (long)(c0 + d) * 1024 + r0 + tc) = v;
    }
}

// ---------------- post: softmax-scatter, vectorized output-position stores ----------------
// Each block owns one row (b,i) of logits (1024 wide, 999 real). Output row:
// out[p] = 0 (p==i or p>=1000); e[p]/sum (p<i); e[p-1]/sum (p>i). Only the
// "all p > i" case needs a neighbor value (thread t-1's e[3]) -> tiny LDS relay.
__global__ __launch_bounds__(256) void post_kernel(
    f16* __restrict__ buf, const float* __restrict__ abf32)
{
    int bid = blockIdx.x;
    int t = threadIdx.x;
    int i = bid % 1000, b = bid / 1000;
    f16* row = buf + ((long)(b * 1000 + i)) * 1024;
    __shared__ float red[8];
    __shared__ float epv[256];
    int k0 = t * 4;
    f16x4 rv = *(const f16x4*)(row + k0);            // all reads before any write
    float4 ab = *(const float4*)(abf32 + k0);
    float abv[4] = {ab.x, ab.y, ab.z, ab.w};
    float v[4];
    float lmax = -3.4e38f;
    #pragma unroll
    for (int j = 0; j < 4; j++) {
        int k = k0 + j;
        float x = (k < 999) ? (float)rv[j] + abv[j] : -3.4e38f;
        v[j] = x;
        lmax = fmaxf(lmax, x);
    }
    #pragma unroll
    for (int o = 32; o > 0; o >>= 1) lmax = fmaxf(lmax, __shfl_down(lmax, o, 64));
    if ((t & 63) == 0) red[t >> 6] = lmax;
    __syncthreads();
    float gmax = fmaxf(fmaxf(red[0], red[1]), fmaxf(red[2], red[3]));
    float e[4];
    float lsum = 0.f;
    #pragma unroll
    for (int j = 0; j < 4; j++) {
        int k = k0 + j;
        float x = (k < 999) ? __expf(v[j] - gmax) : 0.f;
        e[j] = x;
        lsum += x;
    }
    epv[t] = e[3];
    #pragma unroll
    for (int o = 32; o > 0; o >>= 1) lsum += __shfl_down(lsum, o, 64);
    if ((t & 63) == 0) red[4 + (t >> 6)] = lsum;
    __syncthreads();                                 // also covers epv writes
    float inv = 1.f / (red[4] + red[5] + red[6] + red[7]);
    f16x4 outv;
    if (k0 >= 1000) {                                // tail: all zeros
        #pragma unroll
        for (int j = 0; j < 4; j++) outv[j] = (f16)0.f;
    } else if (k0 + 3 < i) {                         // all p < i: own e's
        #pragma unroll
        for (int j = 0; j < 4; j++) outv[j] = (f16)(e[j] * inv);
    } else if (k0 > i) {                             // all p > i: shift by one
        float ep = epv[t - 1];                       // t>=1 guaranteed (k0>i>=0)
        outv[0] = (f16)(ep * inv);
        #pragma unroll
        for (int j = 1; j < 4; j++) outv[j] = (f16)(e[j - 1] * inv);
    } else {                                         // straddle: i in [k0, k0+3]
        #pragma unroll
        for (int j = 0; j < 4; j++) {
            int p = k0 + j;
            float s = (p == i) ? 0.f : ((p < i) ? e[j] : e[j - 1 < 0 ? 0 : j - 1]);
            if (p > i) s = e[j - 1];                 // p>i implies j>=1 here
            outv[j] = (f16)(s * inv);
        }
    }
    *(f16x4*)(row + k0) = outv;
}

// ---------------- 8-phase 256x256 MFMA GEMM (T2+T3+T4+T5) ----------------
// 512 thr = 8 waves (2M x 4N), per-wave 128x64 out, BK=64, dbuf LDS 128 KiB.
#define SB8   __builtin_amdgcn_sched_barrier(0)
#define BAR8  __builtin_amdgcn_s_barrier()
#define LGKM0 do { asm volatile("s_waitcnt lgkmcnt(0)" ::: "memory"); __builtin_amdgcn_sched_barrier(0); } while (0)
#define VM4   asm volatile("s_waitcnt vmcnt(4)" ::: "memory")

__global__ __launch_bounds__(512, 2) void gemm8p_kernel(
    const f16* __restrict__ A, int lda,
    const f16* __restrict__ Bt, int ldb,
    f16* __restrict__ C, int ldc,
    int M, int MT, int NT, int KT,
    long sA, long sB, long sC)
{
    __shared__ __align__(16) f16 As[2][16384];
    __shared__ __align__(16) f16 Bs[2][16384];
    int t = threadIdx.x;
    int nwg = gridDim.x;
    int orig = blockIdx.x;
    int xcd = orig & 7, lin = orig >> 3;
    int q8 = nwg >> 3, r8 = nwg & 7;                 // bijective XCD swizzle (m204)
    int wgid = (xcd < r8 ? xcd * (q8 + 1) : r8 * (q8 + 1) + (xcd - r8) * q8) + lin;
    int per_b = MT * NT;
    int bz = wgid / per_b;
    int rem = wgid - bz * per_b;
    int mt = rem / NT, nt = rem - mt * NT;
    int m0 = mt * 256, n0 = nt * 256;
    A  += (long)bz * sA;
    Bt += (long)bz * sB;
    C  += (long)bz * sC;
    int w = t >> 6, lane = t & 63;
    int wm = (w >> 2) * 128, wn = (w & 3) * 64;
    int lr = lane & 15, lq = lane >> 4;
    int row0 = t >> 3, slot = t & 7;
    int csw = slot ^ (row0 & 7);                     // pre-swizzled global source

    f32x4 acc[8][4];
    const f32x4 z4 = {0.f, 0.f, 0.f, 0.f};
    #pragma unroll
    for (int i = 0; i < 8; i++)
        #pragma unroll
        for (int j = 0; j < 4; j++) acc[i][j] = z4;

    f16x8 a_[2][2], b_[4][2];

#define STAGE_A8(kt, h, buf) do { \
    int ktc = (kt) < KT ? (kt) : KT - 1; \
    const f16* gp = A + (long)(m0 + (h) * 128 + row0) * lda + ktc * 64 + csw * 8; \
    gl2lds16(gp,                  &As[buf][(h) * 8192 + w * 512]); \
    gl2lds16(gp + 64 * (long)lda, &As[buf][(h) * 8192 + 4096 + w * 512]); \
} while (0)
#define STAGE_B8(kt, h, buf) do { \
    int ktc = (kt) < KT ? (kt) : KT - 1; \
    const f16* gp = Bt + (long)(n0 + (h) * 128 + row0) * ldb + ktc * 64 + csw * 8; \
    gl2lds16(gp,                  &Bs[buf][(h) * 8192 + w * 512]); \
    gl2lds16(gp + 64 * (long)ldb, &Bs[buf][(h) * 8192 + 4096 + w * 512]); \
} while (0)
#define RD_B8(buf) { \
    _Pragma("unroll") for (int n = 0; n < 4; n++) { \
        int r = wn + n * 16 + lr; int rb = r * 64; int x7 = r & 7; \
        _Pragma("unroll") for (int ks = 0; ks < 2; ks++) { \
            int cc = (lq + ks * 4) ^ x7; \
            b_[n][ks] = *(const f16x8*)&Bs[buf][rb + cc * 8]; } } }
#define RD_A8(q, buf) { \
    _Pragma("unroll") for (int m2 = 0; m2 < 2; m2++) { \
        int r = wm + ((q) * 2 + m2) * 16 + lr; int rb = r * 64; int x7 = r & 7; \
        _Pragma("unroll") for (int ks = 0; ks < 2; ks++) { \
            int cc = (lq + ks * 4) ^ x7; \
            a_[m2][ks] = *(const f16x8*)&As[buf][rb + cc * 8]; } } }
#define MFMA16(q) { \
    __builtin_amdgcn_s_setprio(1); \
    _Pragma("unroll") for (int ks = 0; ks < 2; ks++) \
    _Pragma("unroll") for (int m2 = 0; m2 < 2; m2++) \
    _Pragma("unroll") for (int n = 0; n < 4; n++) \
        acc[(q) * 2 + m2][n] = __builtin_amdgcn_mfma_f32_16x16x32_f16( \
            a_[m2][ks], b_[n][ks], acc[(q) * 2 + m2][n], 0, 0, 0); \
    __builtin_amdgcn_s_setprio(0); }

    // prologue: B(0),A(0) -> buf0; B(1) -> buf1; wait oldest 8, keep B(1) in flight
    STAGE_B8(0, 0, 0); STAGE_B8(0, 1, 0);
    STAGE_A8(0, 0, 0); STAGE_A8(0, 1, 0);
    STAGE_B8(1, 0, 1); STAGE_B8(1, 1, 1);
    VM4;
    BAR8;

    int NIT = KT >> 1;
    for (int it = 0; it < NIT; it++) {
        int t0 = 2 * it, t1 = t0 + 1;
        SB8; RD_B8(0); RD_A8(0, 0); STAGE_A8(t1, 0, 1);
        BAR8; LGKM0; MFMA16(0); BAR8;
        SB8; RD_A8(1, 0); STAGE_A8(t1, 1, 1);
        BAR8; LGKM0; MFMA16(1); BAR8;
        SB8; RD_A8(2, 0); STAGE_B8(t0 + 2, 0, 0);
        BAR8; LGKM0; MFMA16(2); BAR8;
        SB8; RD_A8(3, 0); STAGE_B8(t0 + 2, 1, 0);
        BAR8; LGKM0; MFMA16(3); VM4; BAR8;
        SB8; RD_B8(1); RD_A8(0, 1); STAGE_A8(t0 + 2, 0, 0);
        BAR8; LGKM0; MFMA16(0); BAR8;
        SB8; RD_A8(1, 1); STAGE_A8(t0 + 2, 1, 0);
        BAR8; LGKM0; MFMA16(1); BAR8;
        SB8; RD_A8(2, 1); STAGE_B8(t1 + 2, 0, 1);
        BAR8; LGKM0; MFMA16(2); BAR8;
        SB8; RD_A8(3, 1); STAGE_B8(t1 + 2, 1, 1);
        BAR8; LGKM0; MFMA16(3); VM4; BAR8;
    }

    // epilogue: C/D layout col=lane&15, row=(lane>>4)*4+reg
    #pragma unroll
    for (int m = 0; m < 8; m++)
        #pragma unroll
        for (int n = 0; n < 4; n++)
            #pragma unroll
            for (int r = 0; r < 4; r++) {
                int gm = m0 + wm + m * 16 + lq * 4 + r;
                int gn = n0 + wn + n * 16 + lr;
                if (gm < M) C[(long)gm * ldc + gn] = (f16)acc[m][n][r];
            }
#undef STAGE_A8
#undef STAGE_B8
#undef RD_B8
#undef RD_A8
#undef MFMA16
}

// ---------------- MFMA GEMM (GEMMW BG path + GEMMS batched final) ----------------
enum { OUT_F16 = 0, OUT_FINAL = 1 };

template<int MODE, bool CAT, bool BKM, int TM, int TN, int BK, int SWZ, bool BG>
__global__ __launch_bounds__(256, 2) void gemm_kernel(
    const f16* __restrict__ A, const f16* __restrict__ A2, int lda,
    const f16* __restrict__ Bt, int ldb,
    void* __restrict__ Cout, int ldc,
    int M, int Nc, int K,
    long sA, long sB, long sC,
    const float* __restrict__ bias, const void* __restrict__ anchors,
    const int* __restrict__ flags, const f16* __restrict__ F2c)
{
    int t = threadIdx.x;
    int bx, by, bz;
    bx = blockIdx.x; by = blockIdx.y; bz = blockIdx.z;

    int m0 = by * TM, n0 = bx * TN;
    int z = bz;
    A  += (long)z * sA;
    if (CAT) A2 += (long)z * sA;
    Bt += (long)z * sB;
    int w = t >> 6, lane = t & 63;
    constexpr int NJ = (TM == 128 && TN == 256) ? 8 : ((TN == 256) ? 4 : ((TM == 128) ? 4 : 2));
    int wm = (TM == 128) ? (w & 1) * 64 : 0;
    int wn;
    if constexpr (TM == 128 && TN == 256) wn = (w >> 1) * 128;
    else if constexpr (TN == 256)         wn = w * 64;
    else if constexpr (TM == 128)         wn = (w >> 1) * 64;
    else                                  wn = w * 32;

    int lr = lane & 15, lq = lane >> 4;

    const f32x4 zero4 = {0.f, 0.f, 0.f, 0.f};
    f32x4 acc[4][NJ];
    #pragma unroll
    for (int i = 0; i < 4; i++)
        #pragma unroll
        for (int j = 0; j < NJ; j++) acc[i][j] = zero4;

    if constexpr (BG) {
        // A staged to LDS; B fragments straight from global (B must be L2-hot & row-padded)
        constexpr int CH  = BK / 8;
        constexpr int AI  = TM * BK / 2048;
        constexpr int RPO = 2048 / BK;
        __shared__ __align__(16) f16 As[TM * BK];
        int row0 = t / CH, slot = t % CH;
        int csw = slot ^ (row0 & (CH - 1));
        long aoffB = (long)(m0 + row0) * lda + csw * 8;
        for (int k0 = 0; k0 < K; k0 += BK) {
            const f16* Ak = A; int kk = k0;
            if (CAT && k0 >= 768) { Ak = A2; kk = k0 - 768; }
            __syncthreads();
            #pragma unroll
            for (int i = 0; i < AI; i++)
                gl2lds16(Ak + aoffB + (long)(i * RPO) * lda + kk, &As[i * 2048 + w * 512]);
            f16x8 ball[BK / 32][NJ];
            #pragma unroll
            for (int ks = 0; ks < BK / 32; ks++)
                #pragma unroll
                for (int j = 0; j < NJ; j++) {
                    int r = wn + j * 16 + lr;
                    ball[ks][j] = *(const f16x8*)(Bt + (long)(n0 + r) * ldb + k0 + (ks * 4 + lq) * 8);
                }
            __syncthreads();
            #pragma unroll
            for (int ks = 0; ks < BK / 32; ks++) {
                f16x8 af[4];
                #pragma unroll
                for (int i = 0; i < 4; i++) {
                    int r = wm + i * 16 + lr;
                    int cc = (lq + ks * 4) ^ (r & (CH - 1));
                    af[i] = *(const f16x8*)&As[r * BK + cc * 8];
                }
                #pragma unroll
                for (int i = 0; i < 4; i++)
                    #pragma unroll
                    for (int j = 0; j < NJ; j++)
                        acc[i][j] = __builtin_amdgcn_mfma_f32_16x16x32_f16(af[i], ball[ks][j], acc[i][j], 0, 0, 0);
            }
        }
    } else {
        constexpr int CH  = BK / 8;                  // 16B chunks per row
        constexpr int AI  = TM * BK / 2048;          // staging ops (2048 elems each)
        constexpr int BI  = TN * BK / 2048;
        constexpr int RPO = 2048 / BK;               // rows per staging op
        __shared__ __align__(16) f16 As[TM * BK];
        __shared__ __align__(16) f16 Bs[TN * BK];
        int row0 = t / CH, slot = t % CH;
        int csw = slot ^ (row0 & (CH - 1));
        long aoffB = (long)(m0 + row0) * lda + csw * 8;
        long boffB = (long)(n0 + row0) * ldb + csw * 8;
        for (int k0 = 0; k0 < K; k0 += BK) {
            const f16* Ak = A; int kk = k0;
            if (CAT && k0 >= 768) { Ak = A2; kk = k0 - 768; }
            __syncthreads();
            #pragma unroll
            for (int i = 0; i < AI; i++)
                gl2lds16(Ak + aoffB + (long)(i * RPO) * lda + kk, &As[i * 2048 + w * 512]);
            #pragma unroll
            for (int i = 0; i < BI; i++)
                gl2lds16(Bt + boffB + (long)(i * RPO) * ldb + k0, &Bs[i * 2048 + w * 512]);
            __syncthreads();                         // drains vmcnt before barrier
            #pragma unroll
            for (int ks = 0; ks < BK / 32; ks++) {
                f16x8 af[4], bfr[NJ];
                #pragma unroll
                for (int i = 0; i < 4; i++) {
                    int r = wm + i * 16 + lr;
                    int cc = (lq + ks * 4) ^ (r & (CH - 1));
                    af[i] = *(const f16x8*)&As[r * BK + cc * 8];
                }
                #pragma unroll
                for (int j = 0; j < NJ; j++) {
                    int r = wn + j * 16 + lr;
                    int cc = (lq + ks * 4) ^ (r & (CH - 1));
                    bfr[j] = *(const f16x8*)&Bs[r * BK + cc * 8];
                }
                #pragma unroll
                for (int i = 0; i < 4; i++)
                    #pragma unroll
                    for (int j = 0; j < NJ; j++)
                        acc[i][j] = __builtin_amdgcn_mfma_f32_16x16x32_f16(af[i], bfr[j], acc[i][j], 0, 0, 0);
            }
        }
    }

    int isf = (MODE == OUT_FINAL) ? flags[1] : 0;
    #pragma unroll
    for (int i = 0; i < 4; i++) {
        #pragma unroll
        for (int j = 0; j < NJ; j++) {
            #pragma unroll
            for (int r = 0; r < 4; r++) {
                int gm = m0 + wm + i * 16 + lq * 4 + r;   // C/D: row = quad*4+reg
                int gn = n0 + wn + j * 16 + lr;           //      col = lane&15
                if (MODE == OUT_F16) {
                    if (gm < M && gn < Nc)
                        ((f16*)Cout)[(long)z * sC + (long)gm * ldc + gn] = (f16)acc[i][j][r];
                } else {
                    if (gm < M) {
                        if (gn < Nc) {                     // Nc=75 real cols
                            float v = acc[i][j][r] + bias[gn];
                            if (F2c) v += (float)F2c[((long)z * 1000 + gm) * 256 + 128 + gn];
                            int oc = (gn < 2) ? gn : gn + 2;   // skip anchor cols 2,3
                            if (gn >= 2) v += ldf(anchors, (long)(gm % 1000) * 77 + oc, isf);
                            stf(Cout, (long)z * sC + (long)gm * 77 + oc, isf, v);
                        } else if (gn < 77) {              // wasted lanes fill anchor cols 2,3
                            int oc = gn - 73;              // 75->2, 76->3
                            stf(Cout, (long)z * sC + (long)gm * 77 + oc, isf,
                                ldf(anchors, (long)(gm % 1000) * 77 + oc, isf));
                        }
                    }
                }
            }
        }
    }
}

extern "C" void kernel_launch(void* const* d_in, const int* in_sizes, int n_in,
                              void* d_out, int out_size, void* d_ws, size_t ws_size,
                              hipStream_t stream)
{
    const void* fv      = d_in[0];
    const void* attn_w  = d_in[1];
    const void* attn_b  = d_in[2];
    const void* cls_w   = d_in[3];
    const void* cls_b   = d_in[4];
    const void* reg_w   = d_in[5];
    const void* reg_b   = d_in[6];
    const void* anchors = d_in[7];
    const int*  x_idx   = (const int*)d_in[10];
    const void* maskp   = d_in[11];
    int xstride = (in_sizes[10] < 768000) ? 12 : 768;   // un-broadcast fallback
    int mstride = (in_sizes[11] < 768000) ? 12 : 768;
    int mwords  = in_sizes[11] / 4;                      // int8 worst case, stay in bounds
    if (mwords > 4096) mwords = 4096;

    char* ws = (char*)d_ws;
    f16*   logits = (f16*)(ws + OFF_LOGITS);
    f16*   feat   = (f16*)(ws + OFF_FEAT);
    f16*   F12    = (f16*)(ws + OFF_F12);
    f16*   awT    = (f16*)(ws + OFF_AWT);
    f16*   wcT2   = (f16*)(ws + OFF_WCT);
    float* biasc  = (float*)(ws + OFF_BIAS);
    float* abf32  = (float*)(ws + OFF_AB);
    int*   flags  = (int*)(ws + OFF_FLAG);
    f16*   F1T    = (f16*)(ws + OFF_F1T);

    detect_kernel<<<dim3(1), dim3(256), 0, stream>>>(
        (const unsigned int*)fv, (const unsigned int*)maskp, mwords, flags);
    front_kernel<<<dim3(2048), dim3(256), 0, stream>>>(
        fv, x_idx, maskp, flags, xstride, mstride, feat,
        attn_w, cls_w, cls_b, reg_w, reg_b, attn_b, awT, wcT2, biasc, abf32);

    // GEMMW: F12 = feat @ [Wc1|Wc2]  (M=32000, N=256, K=768); B=wcT2 L2-hot (BG),
    // A-only LDS, BK=128, TM=64/TN=128 -> 1000 blocks
    gemm_kernel<OUT_F16, false, false, 64, 128, 128, 0, true><<<dim3(2, 500, 1), dim3(256), 0, stream>>>(
        feat, nullptr, 768, wcT2, 768, F12, 256, 32000, 256, 768, 0, 0, 0,
        nullptr, nullptr, flags, nullptr);
    // transpose F1 (F12 cols 0..127) -> F1T per batch (128 x 1024)
    transpf1_kernel<<<dim3(1024), dim3(256), 0, stream>>>(F12, F1T);

    // GEMM1: logits = feat @ attn_w  (M=32000, N=1024 padded, K=768), 8-phase 256^2
    gemm8p_kernel<<<dim3(500), dim3(512), 0, stream>>>(
        feat, 768, awT, 768, logits, 1024, 32000, 125, 4, 12, 0L, 0L, 0L);
    // softmax-scatter (vectorized stores), one block per row
    post_kernel<<<dim3(32000), dim3(256), 0, stream>>>(logits, abf32);

    // GEMMS: out = S @ F1 + F2 + bias + anchors  (batched M=1000, N=75(128), K=1024)
    // TM=64/TN=128/BK=64 -> 16 mt x 32 batches = 512 blocks, 24 KB LDS (multi-block/CU)
    gemm_kernel<OUT_FINAL, false, false, 64, 128, 64, 0, false><<<dim3(1, 16, 32), dim3(256), 0, stream>>>(
        logits, nullptr, 1024, F1T, 1024, d_out, 77, 1000, 75, 1024,
        1024000L, 131072L, 77000L, biasc, anchors, flags, F12);
}